// Round 15
// baseline (261.268 us; speedup 1.0000x reference)
//
#include <hip/hip_runtime.h>
#include <hip/hip_bf16.h>

using short8 = __attribute__((ext_vector_type(8))) short;          // 8 bf16 (4 VGPR)
using f32x4  = __attribute__((ext_vector_type(4))) float;          // MFMA acc
using u16x4  = __attribute__((ext_vector_type(4))) unsigned short; // 8B bf16 store

#define AS1 __attribute__((address_space(1)))
#define AS3 __attribute__((address_space(3)))

__device__ __forceinline__ unsigned short f2bf(float f) {
    __hip_bfloat16 h = __float2bfloat16(f);    // RNE
    return __builtin_bit_cast(unsigned short, h);
}

__device__ __forceinline__ float exp2_hw(float x) {
    float r;
    asm("v_exp_f32 %0, %1" : "=v"(r) : "v"(x));   // D = 2^S0
    return r;
}

// pi-permutation of key k within a 32-key chunk: position of key k in the
// slot order {4g..4g+3, 16+4g..19+4g} for g = 0..3 (slot = g*8+j).
__device__ __forceinline__ int vperm(int lk) {
    return (lk & ~31) | (((lk >> 2) & 3) * 8) | (((lk >> 4) & 1) * 4) | (lk & 3);
}

// ---------------------------------------------------------------- LN -> bf16
__global__ __launch_bounds__(256) void ln_to_bf16(
    const float* __restrict__ X, const float* __restrict__ gw,
    const float* __restrict__ bw, unsigned short* __restrict__ Y)
{
    const int row = blockIdx.x;
    const int tid = threadIdx.x;
    const float4 v = *(const float4*)(X + (size_t)row * 1024 + tid * 4);
    float s  = v.x + v.y + v.z + v.w;
    float s2 = v.x*v.x + v.y*v.y + v.z*v.z + v.w*v.w;
    #pragma unroll
    for (int off = 1; off < 64; off <<= 1) {
        s  += __shfl_xor(s,  off);
        s2 += __shfl_xor(s2, off);
    }
    __shared__ float rs[4], rq[4];
    if ((tid & 63) == 0) { rs[tid >> 6] = s; rq[tid >> 6] = s2; }
    __syncthreads();
    s  = rs[0] + rs[1] + rs[2] + rs[3];
    s2 = rq[0] + rq[1] + rq[2] + rq[3];
    const float mean = s * (1.f / 1024.f);
    const float var  = s2 * (1.f / 1024.f) - mean * mean;
    const float rstd = rsqrtf(var + 1e-5f);
    const float4 gv = *(const float4*)(gw + tid * 4);
    const float4 bv = *(const float4*)(bw + tid * 4);
    u16x4 o;
    o[0] = f2bf((v.x - mean) * rstd * gv.x + bv.x);
    o[1] = f2bf((v.y - mean) * rstd * gv.y + bv.y);
    o[2] = f2bf((v.z - mean) * rstd * gv.z + bv.z);
    o[3] = f2bf((v.w - mean) * rstd * gv.w + bv.w);
    *(u16x4*)(Y + (size_t)row * 1024 + tid * 4) = o;
}

// -------------------- fused preprocessing: ln1 | cast(mem) | 6 transposes
__global__ __launch_bounds__(256) void prep_fused(
    const float* __restrict__ tgt, const float* __restrict__ ln1g,
    const float* __restrict__ ln1b, unsigned short* __restrict__ XA,
    const float* __restrict__ mem, unsigned short* __restrict__ M16,
    const float* __restrict__ wq, const float* __restrict__ wk,
    const float* __restrict__ wv, const float* __restrict__ wo,
    unsigned short* __restrict__ WQT, unsigned short* __restrict__ WKT,
    unsigned short* __restrict__ WVT, unsigned short* __restrict__ WOT,
    const float* __restrict__ w1, unsigned short* __restrict__ W1T,
    const float* __restrict__ w2, unsigned short* __restrict__ W2T)
{
    __shared__ float t[32][33];
    __shared__ float rs[4], rq[4];
    const int bid = blockIdx.x;
    const int tid = threadIdx.x;
    if (bid < 4096) {                                    // ---- LN(tgt) -> XA
        const int row = bid;
        const float4 v = *(const float4*)(tgt + (size_t)row * 1024 + tid * 4);
        float s  = v.x + v.y + v.z + v.w;
        float s2 = v.x*v.x + v.y*v.y + v.z*v.z + v.w*v.w;
        #pragma unroll
        for (int off = 1; off < 64; off <<= 1) {
            s  += __shfl_xor(s,  off);
            s2 += __shfl_xor(s2, off);
        }
        if ((tid & 63) == 0) { rs[tid >> 6] = s; rq[tid >> 6] = s2; }
        __syncthreads();
        s  = rs[0] + rs[1] + rs[2] + rs[3];
        s2 = rq[0] + rq[1] + rq[2] + rq[3];
        const float mean = s * (1.f / 1024.f);
        const float var  = s2 * (1.f / 1024.f) - mean * mean;
        const float rstd = rsqrtf(var + 1e-5f);
        const float4 gv = *(const float4*)(ln1g + tid * 4);
        const float4 bv = *(const float4*)(ln1b + tid * 4);
        u16x4 o;
        o[0] = f2bf((v.x - mean) * rstd * gv.x + bv.x);
        o[1] = f2bf((v.y - mean) * rstd * gv.y + bv.y);
        o[2] = f2bf((v.z - mean) * rstd * gv.z + bv.z);
        o[3] = f2bf((v.w - mean) * rstd * gv.w + bv.w);
        *(u16x4*)(XA + (size_t)row * 1024 + tid * 4) = o;
    } else if (bid < 8192) {                             // ---- cast mem -> M16
        const int i = (bid - 4096) * 256 + tid;          // n4 = 1048576 exact
        float4 v = ((const float4*)mem)[i];
        u16x4 o = { f2bf(v.x), f2bf(v.y), f2bf(v.z), f2bf(v.w) };
        ((u16x4*)M16)[i] = o;
    } else {                                             // ---- transposes
        const float* W; unsigned short* Wt; int kb, nb, K;
        if (bid < 12288) {
            const int idx2 = bid - 8192;
            const int which = idx2 >> 10;
            W  = which == 0 ? wq : which == 1 ? wk : which == 2 ? wv : wo;
            Wt = which == 0 ? WQT : which == 1 ? WKT : which == 2 ? WVT : WOT;
            const int idx = idx2 & 1023;
            kb = idx & 31; nb = idx >> 5; K = 1024;
            const int c = tid & 31, r0 = tid >> 5;
            #pragma unroll
            for (int i = 0; i < 4; i++)
                t[r0 + i * 8][c] = W[(size_t)(kb * 32 + r0 + i * 8) * 1024 + nb * 32 + c];
            __syncthreads();
            #pragma unroll
            for (int i = 0; i < 4; i++)
                Wt[(size_t)(nb * 32 + r0 + i * 8) * K + kb * 32 + c] = f2bf(t[c][r0 + i * 8]);
        } else {
            int N;
            if (bid < 16384) { const int idx = bid - 12288; kb = idx % 32;  nb = idx / 32;  K = 1024; N = 4096; W = w1; Wt = W1T; }
            else             { const int idx = bid - 16384; kb = idx % 128; nb = idx / 128; K = 4096; N = 1024; W = w2; Wt = W2T; }
            const int c = tid & 31, r0 = tid >> 5;
            #pragma unroll
            for (int i = 0; i < 4; i++)
                t[r0 + i * 8][c] = W[(size_t)(kb * 32 + r0 + i * 8) * N + nb * 32 + c];
            __syncthreads();
            #pragma unroll
            for (int i = 0; i < 4; i++)
                Wt[(size_t)(nb * 32 + r0 + i * 8) * K + kb * 32 + c] = f2bf(t[c][r0 + i * 8]);
        }
    }
}

// ------------------------------------------- shared GEMM epilogue (EPI dispatch)
template<int EPI, int BN>
__device__ __forceinline__ void gemm_epilogue(
    f32x4 (&acc)[4][BN / 32], int bm, int bn, int wm, int wn, int g, int q16,
    const float* __restrict__ bias, const float* __restrict__ bias2,
    void* __restrict__ outp, void* __restrict__ outp2,
    const float* __restrict__ resid, float oscale, int N)
{
    constexpr int NF = BN / 32;
    const int row0 = bm * 128 + wm * 64;
    const int col0 = bn * BN + wn * (BN / 2);
    const bool isV = (EPI == 4) && (bn * BN >= 1024);
    #pragma unroll
    for (int nf = 0; nf < NF; nf++) {
        const int col = col0 + nf * 16 + q16;
        const float bv = (EPI == 4 && isV) ? bias2[col - 1024] : bias[col];
        #pragma unroll
        for (int mf = 0; mf < 4; mf++) {
            const int rbase = row0 + mf * 16 + g * 4;
            #pragma unroll
            for (int r = 0; r < 4; r++) {
                const int row = rbase + r;
                const float v = acc[mf][nf][r] + bv;
                if constexpr (EPI == 0) {
                    ((unsigned short*)outp)[(size_t)row * N + col] = f2bf(v * oscale);
                } else if constexpr (EPI == 1) {
                    const int bI = row >> 10, lk = row & 1023, hh = col >> 6, dd = col & 63;
                    ((unsigned short*)outp)[((size_t)(bI * 16 + hh) * 64 + dd) * 1024 + vperm(lk)] = f2bf(v);
                } else if constexpr (EPI == 2) {
                    ((unsigned short*)outp)[(size_t)row * N + col] = f2bf(v > 0.f ? v : 0.f);
                } else if constexpr (EPI == 3) {
                    ((float*)outp)[(size_t)row * N + col] = resid[(size_t)row * N + col] + v;
                } else {  // EPI == 4: fused K/V projection, N==2048
                    if (!isV) {
                        ((unsigned short*)outp)[(size_t)row * 1024 + col] = f2bf(v);
                    } else {
                        const int cc = col - 1024;
                        const int bI = row >> 10, lk = row & 1023, hh = cc >> 6, dd = cc & 63;
                        ((unsigned short*)outp2)[((size_t)(bI * 16 + hh) * 64 + dd) * 1024 + vperm(lk)] = f2bf(v);
                    }
                }
            }
        }
    }
}

// ---------------- GEMM body (m97 + T1 swizzle + T3 2-phase dbuf; r11-proven)
template<int EPI, int BN, int PF>
__device__ __forceinline__ void gemm_body(
    unsigned short* S,
    const unsigned short* __restrict__ A, const unsigned short* __restrict__ Bt,
    const float* __restrict__ bias, const float* __restrict__ bias2,
    void* __restrict__ outp, void* __restrict__ outp2,
    const float* __restrict__ resid, float oscale, int M, int N, int K,
    int vbid, int vgrid)
{
    constexpr int NF = BN / 32;                 // frags per wave in N
    constexpr int LDSH = (128 + BN) * 32;       // elems per 32-k slot (A then B)
    const int tid = threadIdx.x;
    const int lane = tid & 63, wave = tid >> 6;
    const int g = lane >> 4, q16 = lane & 15;
    const int wm = wave >> 1, wn = wave & 1;
    const int nb = N / BN;
    const int cpx = vgrid >> 3;
    const int swz = (vbid & 7) * cpx + (vbid >> 3);
    const int bm = swz / nb, bn = swz % nb;

    const unsigned short* aSrc = A  + (size_t)(bm * 128 + (tid >> 2)) * K + (tid & 3) * 8;
    const unsigned short* bSrc = Bt + (size_t)(bn * BN  + (tid >> 2)) * K + (tid & 3) * 8;
    const size_t rowStep = (size_t)64 * K;

    f32x4 acc[4][NF] = {};

    auto STAGE = [&](int slot, int kt) {
        unsigned short* aDst = &S[slot * LDSH] + wave * 512;       // wave-uniform base
        unsigned short* bDst = &S[slot * LDSH + 4096] + wave * 512;
        __builtin_amdgcn_global_load_lds((const AS1 unsigned int*)(aSrc + kt),           (AS3 unsigned int*)aDst,          16, 0, 0);
        __builtin_amdgcn_global_load_lds((const AS1 unsigned int*)(aSrc + rowStep + kt), (AS3 unsigned int*)(aDst + 2048), 16, 0, 0);
        __builtin_amdgcn_global_load_lds((const AS1 unsigned int*)(bSrc + kt),           (AS3 unsigned int*)bDst,          16, 0, 0);
        if constexpr (BN == 128)
            __builtin_amdgcn_global_load_lds((const AS1 unsigned int*)(bSrc + rowStep + kt), (AS3 unsigned int*)(bDst + 2048), 16, 0, 0);
    };
    auto COMPUTE = [&](int slot) {
        const unsigned short* As = &S[slot * LDSH];
        const unsigned short* Bs = As + 4096;
        short8 af[4], bfr[NF];
        #pragma unroll
        for (int i = 0; i < 4; i++)  af[i]  = *(const short8*)(As + (wm * 64 + i * 16 + q16) * 32 + g * 8);
        #pragma unroll
        for (int i = 0; i < NF; i++) bfr[i] = *(const short8*)(Bs + (wn * (BN / 2) + i * 16 + q16) * 32 + g * 8);
        #pragma unroll
        for (int mf = 0; mf < 4; mf++)
            #pragma unroll
            for (int nf = 0; nf < NF; nf++)
                acc[mf][nf] = __builtin_amdgcn_mfma_f32_16x16x32_bf16(af[mf], bfr[nf], acc[mf][nf], 0, 0, 0);
    };

    #pragma unroll
    for (int i = 0; i < PF; i++) STAGE(i, i * 32);
    __syncthreads();                 // drain: slots [0,PF) ready
    int p = 0;
    #pragma unroll 1
    for (int kt = PF * 32; kt < K; kt += PF * 32) {
        #pragma unroll
        for (int i = 0; i < PF; i++) STAGE((p ^ 1) * PF + i, kt + i * 32);  // prefetch pair
        #pragma unroll
        for (int i = 0; i < PF; i++) COMPUTE(p * PF + i);
        __syncthreads();             // next slots ready; current free for overwrite
        p ^= 1;
    }
    #pragma unroll
    for (int i = 0; i < PF; i++) COMPUTE(p * PF + i);   // tail (no prefetch)

    gemm_epilogue<EPI, BN>(acc, bm, bn, wm, wn, g, q16, bias, bias2,
                           outp, outp2, resid, oscale, N);
}

template<int EPI, int BN, int PF>
__global__ __launch_bounds__(256) void gemm_single(
    const unsigned short* __restrict__ A, const unsigned short* __restrict__ Bt,
    const float* __restrict__ bias, const float* __restrict__ bias2,
    void* __restrict__ outp, void* __restrict__ outp2,
    const float* __restrict__ resid, float oscale, int M, int N, int K)
{
    __shared__ unsigned short S[2 * PF * (128 + BN) * 32];
    gemm_body<EPI, BN, PF>(S, A, Bt, bias, bias2, outp, outp2, resid, oscale,
                           M, N, K, blockIdx.x, gridDim.x);
}

// -------- GEMM 3-buffer ring: stage-early, counted vmcnt, ONE non-draining
// s_barrier per pair (T4). Invariants: COMPUTE(T_t) — T_t completed by iter
// t-1's vmcnt(LPP) (outstanding then = T_t remnant + T_{t+1} -> waits T_t) and
// made visible by its barrier. STAGE at t targets pair (t+2)%3 = (t-1)%3 whose
// readers finished at t-1's barrier. T_{t+1} waited at end of t after a full
// COMPUTE (~450cy) of cover -> ~zero exposed load latency, no vmcnt(0) drain.
template<int EPI, int BN, int PF>
__global__ __launch_bounds__(256) void gemm_ring3(
    const unsigned short* __restrict__ A, const unsigned short* __restrict__ Bt,
    const float* __restrict__ bias, const float* __restrict__ bias2,
    void* __restrict__ outp, void* __restrict__ outp2,
    const float* __restrict__ resid, float oscale, int M, int N, int K)
{
    constexpr int NF = BN / 32;
    constexpr int LDSH = (128 + BN) * 32;
    constexpr int LPP = PF * (BN == 128 ? 4 : 3);   // gload_lds per pair per wave
    __shared__ unsigned short S[3 * PF * LDSH];     // 3 pairs
    const int tid = threadIdx.x;
    const int lane = tid & 63, wave = tid >> 6;
    const int g = lane >> 4, q16 = lane & 15;
    const int wm = wave >> 1, wn = wave & 1;
    const int nb = N / BN;
    const int cpx = gridDim.x >> 3;
    const int swz = (blockIdx.x & 7) * cpx + (blockIdx.x >> 3);
    const int bm = swz / nb, bn = swz % nb;

    const unsigned short* aSrc = A  + (size_t)(bm * 128 + (tid >> 2)) * K + (tid & 3) * 8;
    const unsigned short* bSrc = Bt + (size_t)(bn * BN  + (tid >> 2)) * K + (tid & 3) * 8;
    const size_t rowStep = (size_t)64 * K;

    f32x4 acc[4][NF] = {};

    auto STAGEPAIR = [&](int pair, int t) {
        #pragma unroll
        for (int i = 0; i < PF; i++) {
            const int kt = t * PF * 32 + i * 32;
            unsigned short* aDst = &S[(pair * PF + i) * LDSH] + wave * 512;
            unsigned short* bDst = &S[(pair * PF + i) * LDSH + 4096] + wave * 512;
            __builtin_amdgcn_global_load_lds((const AS1 unsigned int*)(aSrc + kt),           (AS3 unsigned int*)aDst,          16, 0, 0);
            __builtin_amdgcn_global_load_lds((const AS1 unsigned int*)(aSrc + rowStep + kt), (AS3 unsigned int*)(aDst + 2048), 16, 0, 0);
            __builtin_amdgcn_global_load_lds((const AS1 unsigned int*)(bSrc + kt),           (AS3 unsigned int*)bDst,          16, 0, 0);
            if constexpr (BN == 128)
                __builtin_amdgcn_global_load_lds((const AS1 unsigned int*)(bSrc + rowStep + kt), (AS3 unsigned int*)(bDst + 2048), 16, 0, 0);
        }
    };
    auto COMPUTEPAIR = [&](int pair) {
        #pragma unroll
        for (int s = 0; s < PF; s++) {
            const unsigned short* As = &S[(pair * PF + s) * LDSH];
            const unsigned short* Bs = As + 4096;
            short8 af[4], bfr[NF];
            #pragma unroll
            for (int i = 0; i < 4; i++)  af[i]  = *(const short8*)(As + (wm * 64 + i * 16 + q16) * 32 + g * 8);
            #pragma unroll
            for (int i = 0; i < NF; i++) bfr[i] = *(const short8*)(Bs + (wn * (BN / 2) + i * 16 + q16) * 32 + g * 8);
            #pragma unroll
            for (int mf = 0; mf < 4; mf++)
                #pragma unroll
                for (int nf = 0; nf < NF; nf++)
                    acc[mf][nf] = __builtin_amdgcn_mfma_f32_16x16x32_bf16(af[mf], bfr[nf], acc[mf][nf], 0, 0, 0);
        }
    };

    const int NT = K / (PF * 32);           // >= 3 for FFN2 (64)
    STAGEPAIR(0, 0);
    STAGEPAIR(1, 1);
    asm volatile("s_waitcnt vmcnt(%0)" :: "n"(LPP) : "memory");   // T0 done
    __builtin_amdgcn_s_barrier();                                  // T0 visible
    #pragma unroll 1
    for (int t = 0; t < NT; ++t) {
        if (t + 2 < NT) STAGEPAIR((t + 2) % 3, t + 2);   // overwrite pair read at t-1
        COMPUTEPAIR(t % 3);                               // T_t done+visible
        if (t + 1 < NT) asm volatile("s_waitcnt vmcnt(%0)" :: "n"(LPP) : "memory");
        else            asm volatile("s_waitcnt vmcnt(0)" ::: "memory");
        __builtin_amdgcn_s_barrier();                     // T_{t+1} visible; readers done
    }

    gemm_epilogue<EPI, BN>(acc, bm, bn, wm, wn, g, q16, bias, bias2,
                           outp, outp2, resid, oscale, N);
}

// ------------- fused Q + KV projections (independent; one 1024-block launch)
__global__ __launch_bounds__(256) void qkv_fused(
    const unsigned short* __restrict__ XA, const unsigned short* __restrict__ WQT,
    const float* __restrict__ bq,
    const unsigned short* __restrict__ M16, const unsigned short* __restrict__ WKT,
    const float* __restrict__ bk, const float* __restrict__ bv,
    unsigned short* __restrict__ Qb, unsigned short* __restrict__ Kb,
    unsigned short* __restrict__ Vt, float qscale)
{
    __shared__ unsigned short S[2 * 2 * 256 * 32];   // 64 KB (max of the two shapes)
    if (blockIdx.x < 512)
        gemm_body<0, 64, 2>(S, XA, WQT, bq, nullptr, Qb, nullptr, nullptr,
                            qscale, 4096, 1024, 1024, blockIdx.x, 512);
    else
        gemm_body<4, 128, 2>(S, M16, WKT, bk, bv, Kb, Vt, nullptr,
                             1.0f, 4096, 2048, 1024, blockIdx.x - 512, 512);
}

// ------------------------------------------------------------- attention PV
__global__ __launch_bounds__(256) void att_pv(
    const unsigned short* __restrict__ Q, const unsigned short* __restrict__ Kb,
    const unsigned short* __restrict__ Vt, unsigned short* __restrict__ O,
    float* __restrict__ LINV)
{
    __shared__ unsigned short Ks[2][2048];   // [32k][64d], swizzled 16B slots
    __shared__ unsigned short Vs[2][2048];   // [64d][32k], swizzled 16B slots
    const int tid = threadIdx.x, lane = tid & 63, wave = tid >> 6;
    const int g = lane >> 4, q16 = lane & 15;
    const int bh = blockIdx.x & 63;     // stride-64 blocks share (b,h) -> same XCD
    const int qt = blockIdx.x >> 6;     // 0..7
    const int b = bh >> 4, h = bh & 15;
    const int qbase = qt * 128 + wave * 32;

    const int rowK = wave * 8 + (lane >> 3);          // k-row within chunk
    const int cK   = (lane & 7) ^ (rowK & 7);         // swizzled 16B slot
    const int rowV = wave * 16 + (lane >> 2);         // d-row
    const int cV   = (lane & 3) ^ (rowV & 3);
    const unsigned short* kSrc = Kb + ((size_t)(b * 1024 + rowK)) * 1024 + h * 64 + cK * 8;
    const unsigned short* vSrc = Vt + ((size_t)(bh * 64 + rowV)) * 1024 + cV * 8;

    short8 qf[2][2];
    #pragma unroll
    for (int nf = 0; nf < 2; nf++)
        #pragma unroll
        for (int ds = 0; ds < 2; ds++)
            qf[nf][ds] = *(const short8*)(Q + (size_t)(b * 1024 + qbase + nf * 16 + q16) * 1024 + h * 64 + ds * 32 + g * 8);

    f32x4 oacc[4][2] = {};
    float lsum[2] = {0.f, 0.f};

    auto STAGE = [&](int buf, int kc) {
        __builtin_amdgcn_global_load_lds((const AS1 unsigned int*)(kSrc + (size_t)kc * 1024),
                                         (AS3 unsigned int*)(&Ks[buf][0] + wave * 512), 16, 0, 0);
        __builtin_amdgcn_global_load_lds((const AS1 unsigned int*)(vSrc + kc),
                                         (AS3 unsigned int*)(&Vs[buf][0] + wave * 512), 16, 0, 0);
    };
    auto BODY = [&](int buf) {
        short8 kf[2][2], vf[4];
        #pragma unroll
        for (int kt = 0; kt < 2; kt++)
            #pragma unroll
            for (int ds = 0; ds < 2; ds++)
                kf[kt][ds] = *(const short8*)(&Ks[buf][0] + (kt * 16 + q16) * 64 + ((ds * 4 + g) ^ (q16 & 7)) * 8);
        #pragma unroll
        for (int mf = 0; mf < 4; mf++)
            vf[mf] = *(const short8*)(&Vs[buf][0] + (mf * 16 + q16) * 32 + (g ^ (q16 & 3)) * 8);
        f32x4 sacc[2][2] = {};
        #pragma unroll
        for (int kt = 0; kt < 2; kt++)
            #pragma unroll
            for (int nf = 0; nf < 2; nf++) {
                sacc[kt][nf] = __builtin_amdgcn_mfma_f32_16x16x32_bf16(kf[kt][0], qf[nf][0], sacc[kt][nf], 0, 0, 0);
                sacc[kt][nf] = __builtin_amdgcn_mfma_f32_16x16x32_bf16(kf[kt][1], qf[nf][1], sacc[kt][nf], 0, 0, 0);
            }
        float ps[2][2][4];
        #pragma unroll
        for (int kt = 0; kt < 2; kt++)
            #pragma unroll
            for (int nf = 0; nf < 2; nf++)
                #pragma unroll
                for (int r = 0; r < 4; r++)
                    ps[kt][nf][r] = exp2_hw(sacc[kt][nf][r]);
        #pragma unroll
        for (int nf = 0; nf < 2; nf++)
            lsum[nf] += ps[0][nf][0] + ps[0][nf][1] + ps[0][nf][2] + ps[0][nf][3]
                      + ps[1][nf][0] + ps[1][nf][1] + ps[1][nf][2] + ps[1][nf][3];
        short8 pbf[2];
        #pragma unroll
        for (int nf = 0; nf < 2; nf++) {
            pbf[nf][0] = (short)f2bf(ps[0][nf][0]);
            pbf[nf][1] = (short)f2bf(ps[0][nf][1]);
            pbf[nf][2] = (short)f2bf(ps[0][nf][2]);
            pbf[nf][3] = (short)f2bf(ps[0][nf][3]);
            pbf[nf][4] = (short)f2bf(ps[1][nf][0]);
            pbf[nf][5] = (short)f2bf(ps[1][nf][1]);
            pbf[nf][6] = (short)f2bf(ps[1][nf][2]);
            pbf[nf][7] = (short)f2bf(ps[1][nf][3]);
        }
        #pragma unroll
        for (int mf = 0; mf < 4; mf++)
            #pragma unroll
            for (int nf = 0; nf < 2; nf++)
                oacc[mf][nf] = __builtin_amdgcn_mfma_f32_16x16x32_bf16(vf[mf], pbf[nf], oacc[mf][nf], 0, 0, 0);
    };

    STAGE(0, 0);
    __syncthreads();                 // buf0 staged
    int buf = 0;
    #pragma unroll 1
    for (int kc = 0; kc < 1024; kc += 32) {
        if (kc + 32 < 1024) STAGE(buf ^ 1, kc + 32);   // flies under BODY
        BODY(buf);
        __syncthreads();             // next buf ready; cur free for overwrite
        buf ^= 1;
    }
    #pragma unroll
    for (int nf = 0; nf < 2; nf++) {               // deferred cross-lane reduce
        lsum[nf] += __shfl_xor(lsum[nf], 16);
        lsum[nf] += __shfl_xor(lsum[nf], 32);
    }

    #pragma unroll
    for (int nf = 0; nf < 2; nf++) {
        const float inv = 1.0f / lsum[nf];
        if (g == 0) LINV[(size_t)bh * 1024 + qbase + nf * 16 + q16] = inv;
        #pragma unroll
        for (int mf = 0; mf < 4; mf++) {
            u16x4 o;
            #pragma unroll
            for (int r = 0; r < 4; r++) o[r] = f2bf(oacc[mf][nf][r] * inv);
            *(u16x4*)(O + (size_t)(b * 1024 + qbase + nf * 16 + q16) * 1024 + h * 64 + mf * 16 + g * 4) = o;
        }
    }
}

// ------------------------------------------------- head-averaged attn output
__global__ __launch_bounds__(256) void att_mean(
    const unsigned short* __restrict__ Q, const unsigned short* __restrict__ Kb,
    const float* __restrict__ LINV, float* __restrict__ out1)
{
    __shared__ unsigned short Qs[2][2048];   // [32q][64d], swizzled 16B slots
    const int tid = threadIdx.x;
    const int lane = tid & 63, wave = tid >> 6;
    const int g = lane >> 4, q16 = lane & 15;
    const int kb = blockIdx.x & 7;
    const int qb = (blockIdx.x >> 3) & 31;
    const int b = blockIdx.x >> 8;
    const int qbase = qb * 32;
    const int kbase = kb * 128 + wave * 32;

    const int rowQ = wave * 8 + (lane >> 3);
    const int cQ   = (lane & 7) ^ (rowQ & 7);
    const unsigned short* qSrc = Q + (size_t)(b * 1024 + qbase + rowQ) * 1024 + cQ * 8;

    f32x4 facc[2][2] = {};

    auto STAGE = [&](int buf, int h) {
        __builtin_amdgcn_global_load_lds((const AS1 unsigned int*)(qSrc + h * 64),
                                         (AS3 unsigned int*)(&Qs[buf][0] + wave * 512), 16, 0, 0);
    };
    auto LOADK = [&](short8 (&kf)[2][2], f32x4 (&li)[2], int h) {
        #pragma unroll
        for (int nf = 0; nf < 2; nf++)
            #pragma unroll
            for (int ds = 0; ds < 2; ds++)
                kf[nf][ds] = *(const short8*)(Kb + (size_t)(b * 1024 + kbase + nf * 16 + q16) * 1024 + h * 64 + ds * 32 + g * 8);
        const float* lp = LINV + (size_t)(b * 16 + h) * 1024 + qbase;
        #pragma unroll
        for (int mf = 0; mf < 2; mf++)
            li[mf] = *(const f32x4*)(lp + mf * 16 + g * 4);
    };
    auto COMP = [&](int buf, short8 (&kf)[2][2], f32x4 (&li)[2]) {
        short8 qfr[2][2];
        #pragma unroll
        for (int mf = 0; mf < 2; mf++)
            #pragma unroll
            for (int ds = 0; ds < 2; ds++)
                qfr[mf][ds] = *(const short8*)(&Qs[buf][0] + (mf * 16 + q16) * 64 + ((ds * 4 + g) ^ (q16 & 7)) * 8);
        #pragma unroll
        for (int nf = 0; nf < 2; nf++) {
            f32x4 sacc[2] = {};
            #pragma unroll
            for (int mf = 0; mf < 2; mf++) {
                sacc[mf] = __builtin_amdgcn_mfma_f32_16x16x32_bf16(qfr[mf][0], kf[nf][0], sacc[mf], 0, 0, 0);
                sacc[mf] = __builtin_amdgcn_mfma_f32_16x16x32_bf16(qfr[mf][1], kf[nf][1], sacc[mf], 0, 0, 0);
            }
            #pragma unroll
            for (int mf = 0; mf < 2; mf++)
                #pragma unroll
                for (int r = 0; r < 4; r++)
                    facc[mf][nf][r] = fmaf(exp2_hw(sacc[mf][r]), li[mf][r], facc[mf][nf][r]);
        }
    };

    short8 kA[2][2], kB[2][2];
    f32x4 liA[2], liB[2];
    STAGE(0, 0); LOADK(kA, liA, 0);
    __syncthreads();                     // buf0 staged
    #pragma unroll 1
    for (int h = 0; h < 16; h += 2) {
        STAGE(1, h + 1); LOADK(kB, liB, h + 1);     // fly under COMP(buf0)
        COMP(0, kA, liA);
        __syncthreads();                 // buf1 staged; buf0 reads done
        if (h + 2 < 16) { STAGE(0, h + 2); LOADK(kA, liA, h + 2); }
        COMP(1, kB, liB);
        __syncthreads();                 // buf0 staged; buf1 reads done
    }

    #pragma unroll
    for (int mf = 0; mf < 2; mf++)
        #pragma unroll
        for (int nf = 0; nf < 2; nf++)
            #pragma unroll
            for (int r = 0; r < 4; r++)
                out1[(size_t)(b * 1024 + qbase + mf * 16 + g * 4 + r) * 1024 + kbase + nf * 16 + q16]
                    = facc[mf][nf][r] * 0.0625f;
}

// ---------------------------------------------------------------- launcher
extern "C" void kernel_launch(void* const* d_in, const int* in_sizes, int n_in,
                              void* d_out, int out_size, void* d_ws, size_t ws_size,
                              hipStream_t stream)
{
    (void)in_sizes; (void)n_in; (void)out_size; (void)ws_size;
    const float* tgt  = (const float*)d_in[0];
    const float* mem  = (const float*)d_in[1];
    const float* ln1g = (const float*)d_in[2];
    const float* ln1b = (const float*)d_in[3];
    const float* wq   = (const float*)d_in[4];
    const float* bq   = (const float*)d_in[5];
    const float* wk   = (const float*)d_in[6];
    const float* bk   = (const float*)d_in[7];
    const float* wv   = (const float*)d_in[8];
    const float* bv   = (const float*)d_in[9];
    const float* wo   = (const float*)d_in[10];
    const float* bo   = (const float*)d_in[11];
    const float* ln3g = (const float*)d_in[12];
    const float* ln3b = (const float*)d_in[13];
    const float* w1   = (const float*)d_in[14];
    const float* b1   = (const float*)d_in[15];
    const float* w2   = (const float*)d_in[16];
    const float* b2   = (const float*)d_in[17];

    char* ws = (char*)d_ws;
    unsigned short* XA  = (unsigned short*)(ws);                  // 8 MB (t2, later t3)
    unsigned short* M16 = (unsigned short*)(ws + ((size_t)8  << 20));
    unsigned short* WQT = (unsigned short*)(ws + ((size_t)16 << 20));
    unsigned short* WKT = (unsigned short*)(ws + ((size_t)18 << 20)); // [WKT;WVT] = fused 2048xK
    unsigned short* WVT = (unsigned short*)(ws + ((size_t)20 << 20));
    unsigned short* WOT = (unsigned short*)(ws + ((size_t)22 << 20));
    unsigned short* W1T = (unsigned short*)(ws + ((size_t)24 << 20)); // 8 MB
    unsigned short* W2T = (unsigned short*)(ws + ((size_t)32 << 20)); // 8 MB
    unsigned short* Qb  = (unsigned short*)(ws + ((size_t)40 << 20));
    unsigned short* Kb  = (unsigned short*)(ws + ((size_t)48 << 20));
    unsigned short* Vt  = (unsigned short*)(ws + ((size_t)56 << 20));
    unsigned short* O16 = (unsigned short*)(ws + ((size_t)64 << 20));
    unsigned short* H16 = (unsigned short*)(ws + ((size_t)72 << 20)); // 32 MB
    float*          LNV = (float*)(ws + ((size_t)104 << 20));         // 256 KB
    float* xout = (float*)d_out;                       // x then x+ffn [4096][1024]
    float* attn = xout + (size_t)4 * 1024 * 1024;      // [4][1024][1024]

    const float QSCALE = 0.125f * 1.4426950408889634f;   // fold softmax scale + log2e into Q

    prep_fused<<<20480, 256, 0, stream>>>(tgt, ln1g, ln1b, XA, mem, M16,
                                          wq, wk, wv, wo, WQT, WKT, WVT, WOT,
                                          w1, W1T, w2, W2T);

    // fused Q (prescaled, EPI0/BN64) + KV (EPI4/BN128) projections, grid 1024
    qkv_fused<<<1024, 256, 0, stream>>>(XA, WQT, bq, M16, WKT, bk, bv, Qb, Kb, Vt, QSCALE);

    att_pv<<<512, 256, 0, stream>>>(Qb, Kb, Vt, O16, LNV);
    att_mean<<<1024, 256, 0, stream>>>(Qb, Kb, LNV, attn);

    // WO: N=1024, BN=64, PF=2 -> grid 512 (writes xout = tgt + attn*WO)
    gemm_single<3, 64, 2><<<32 * 16, 256, 0, stream>>>(O16, WOT, bo, nullptr, xout, nullptr, tgt, 1.0f, 4096, 1024, 1024);
    ln_to_bf16<<<4096, 256, 0, stream>>>(xout, ln3g, ln3b, XA);
    // FFN1: N=4096, BN=128, PF=2 -> grid 1024
    gemm_single<2, 128, 2><<<32 * 32, 256, 0, stream>>>(XA, W1T, b1, nullptr, H16, nullptr, nullptr, 1.0f, 4096, 4096, 1024);
    // FFN2: N=1024, K=4096 -> 3-buffer ring (counted vmcnt, no drain), grid 512
    gemm_ring3<3, 64, 2><<<32 * 16, 256, 0, stream>>>(H16, W2T, b2, nullptr, xout, nullptr, xout, 1.0f, 4096, 1024, 4096);
}

// Round 16
// 260.595 us; speedup vs baseline: 1.0026x; 1.0026x over previous
//
#include <hip/hip_runtime.h>
#include <hip/hip_bf16.h>

using short8 = __attribute__((ext_vector_type(8))) short;          // 8 bf16 (4 VGPR)
using f32x4  = __attribute__((ext_vector_type(4))) float;          // MFMA acc
using u16x4  = __attribute__((ext_vector_type(4))) unsigned short; // 8B bf16 store

#define AS1 __attribute__((address_space(1)))
#define AS3 __attribute__((address_space(3)))

__device__ __forceinline__ unsigned short f2bf(float f) {
    __hip_bfloat16 h = __float2bfloat16(f);    // RNE
    return __builtin_bit_cast(unsigned short, h);
}

__device__ __forceinline__ float exp2_hw(float x) {
    float r;
    asm("v_exp_f32 %0, %1" : "=v"(r) : "v"(x));   // D = 2^S0
    return r;
}

// pi-permutation of key k within a 32-key chunk: position of key k in the
// slot order {4g..4g+3, 16+4g..19+4g} for g = 0..3 (slot = g*8+j).
__device__ __forceinline__ int vperm(int lk) {
    return (lk & ~31) | (((lk >> 2) & 3) * 8) | (((lk >> 4) & 1) * 4) | (lk & 3);
}

// ---------------------------------------------------------------- LN -> bf16
__global__ __launch_bounds__(256) void ln_to_bf16(
    const float* __restrict__ X, const float* __restrict__ gw,
    const float* __restrict__ bw, unsigned short* __restrict__ Y)
{
    const int row = blockIdx.x;
    const int tid = threadIdx.x;
    const float4 v = *(const float4*)(X + (size_t)row * 1024 + tid * 4);
    float s  = v.x + v.y + v.z + v.w;
    float s2 = v.x*v.x + v.y*v.y + v.z*v.z + v.w*v.w;
    #pragma unroll
    for (int off = 1; off < 64; off <<= 1) {
        s  += __shfl_xor(s,  off);
        s2 += __shfl_xor(s2, off);
    }
    __shared__ float rs[4], rq[4];
    if ((tid & 63) == 0) { rs[tid >> 6] = s; rq[tid >> 6] = s2; }
    __syncthreads();
    s  = rs[0] + rs[1] + rs[2] + rs[3];
    s2 = rq[0] + rq[1] + rq[2] + rq[3];
    const float mean = s * (1.f / 1024.f);
    const float var  = s2 * (1.f / 1024.f) - mean * mean;
    const float rstd = rsqrtf(var + 1e-5f);
    const float4 gv = *(const float4*)(gw + tid * 4);
    const float4 bv = *(const float4*)(bw + tid * 4);
    u16x4 o;
    o[0] = f2bf((v.x - mean) * rstd * gv.x + bv.x);
    o[1] = f2bf((v.y - mean) * rstd * gv.y + bv.y);
    o[2] = f2bf((v.z - mean) * rstd * gv.z + bv.z);
    o[3] = f2bf((v.w - mean) * rstd * gv.w + bv.w);
    *(u16x4*)(Y + (size_t)row * 1024 + tid * 4) = o;
}

// -------------------- fused preprocessing: ln1 | cast(mem) | 6 transposes
__global__ __launch_bounds__(256) void prep_fused(
    const float* __restrict__ tgt, const float* __restrict__ ln1g,
    const float* __restrict__ ln1b, unsigned short* __restrict__ XA,
    const float* __restrict__ mem, unsigned short* __restrict__ M16,
    const float* __restrict__ wq, const float* __restrict__ wk,
    const float* __restrict__ wv, const float* __restrict__ wo,
    unsigned short* __restrict__ WQT, unsigned short* __restrict__ WKT,
    unsigned short* __restrict__ WVT, unsigned short* __restrict__ WOT,
    const float* __restrict__ w1, unsigned short* __restrict__ W1T,
    const float* __restrict__ w2, unsigned short* __restrict__ W2T)
{
    __shared__ float t[32][33];
    __shared__ float rs[4], rq[4];
    const int bid = blockIdx.x;
    const int tid = threadIdx.x;
    if (bid < 4096) {                                    // ---- LN(tgt) -> XA
        const int row = bid;
        const float4 v = *(const float4*)(tgt + (size_t)row * 1024 + tid * 4);
        float s  = v.x + v.y + v.z + v.w;
        float s2 = v.x*v.x + v.y*v.y + v.z*v.z + v.w*v.w;
        #pragma unroll
        for (int off = 1; off < 64; off <<= 1) {
            s  += __shfl_xor(s,  off);
            s2 += __shfl_xor(s2, off);
        }
        if ((tid & 63) == 0) { rs[tid >> 6] = s; rq[tid >> 6] = s2; }
        __syncthreads();
        s  = rs[0] + rs[1] + rs[2] + rs[3];
        s2 = rq[0] + rq[1] + rq[2] + rq[3];
        const float mean = s * (1.f / 1024.f);
        const float var  = s2 * (1.f / 1024.f) - mean * mean;
        const float rstd = rsqrtf(var + 1e-5f);
        const float4 gv = *(const float4*)(ln1g + tid * 4);
        const float4 bv = *(const float4*)(ln1b + tid * 4);
        u16x4 o;
        o[0] = f2bf((v.x - mean) * rstd * gv.x + bv.x);
        o[1] = f2bf((v.y - mean) * rstd * gv.y + bv.y);
        o[2] = f2bf((v.z - mean) * rstd * gv.z + bv.z);
        o[3] = f2bf((v.w - mean) * rstd * gv.w + bv.w);
        *(u16x4*)(XA + (size_t)row * 1024 + tid * 4) = o;
    } else if (bid < 8192) {                             // ---- cast mem -> M16
        const int i = (bid - 4096) * 256 + tid;          // n4 = 1048576 exact
        float4 v = ((const float4*)mem)[i];
        u16x4 o = { f2bf(v.x), f2bf(v.y), f2bf(v.z), f2bf(v.w) };
        ((u16x4*)M16)[i] = o;
    } else {                                             // ---- transposes
        const float* W; unsigned short* Wt; int kb, nb, K;
        if (bid < 12288) {
            const int idx2 = bid - 8192;
            const int which = idx2 >> 10;
            W  = which == 0 ? wq : which == 1 ? wk : which == 2 ? wv : wo;
            Wt = which == 0 ? WQT : which == 1 ? WKT : which == 2 ? WVT : WOT;
            const int idx = idx2 & 1023;
            kb = idx & 31; nb = idx >> 5; K = 1024;
            const int c = tid & 31, r0 = tid >> 5;
            #pragma unroll
            for (int i = 0; i < 4; i++)
                t[r0 + i * 8][c] = W[(size_t)(kb * 32 + r0 + i * 8) * 1024 + nb * 32 + c];
            __syncthreads();
            #pragma unroll
            for (int i = 0; i < 4; i++)
                Wt[(size_t)(nb * 32 + r0 + i * 8) * K + kb * 32 + c] = f2bf(t[c][r0 + i * 8]);
        } else {
            int N;
            if (bid < 16384) { const int idx = bid - 12288; kb = idx % 32;  nb = idx / 32;  K = 1024; N = 4096; W = w1; Wt = W1T; }
            else             { const int idx = bid - 16384; kb = idx % 128; nb = idx / 128; K = 4096; N = 1024; W = w2; Wt = W2T; }
            const int c = tid & 31, r0 = tid >> 5;
            #pragma unroll
            for (int i = 0; i < 4; i++)
                t[r0 + i * 8][c] = W[(size_t)(kb * 32 + r0 + i * 8) * N + nb * 32 + c];
            __syncthreads();
            #pragma unroll
            for (int i = 0; i < 4; i++)
                Wt[(size_t)(nb * 32 + r0 + i * 8) * K + kb * 32 + c] = f2bf(t[c][r0 + i * 8]);
        }
    }
}

// ------------------------------------------- shared GEMM epilogue (EPI dispatch)
template<int EPI, int BN>
__device__ __forceinline__ void gemm_epilogue(
    f32x4 (&acc)[4][BN / 32], int bm, int bn, int wm, int wn, int g, int q16,
    const float* __restrict__ bias, const float* __restrict__ bias2,
    void* __restrict__ outp, void* __restrict__ outp2,
    const float* __restrict__ resid, float oscale, int N)
{
    constexpr int NF = BN / 32;
    const int row0 = bm * 128 + wm * 64;
    const int col0 = bn * BN + wn * (BN / 2);
    const bool isV = (EPI == 4) && (bn * BN >= 1024);
    #pragma unroll
    for (int nf = 0; nf < NF; nf++) {
        const int col = col0 + nf * 16 + q16;
        const float bv = (EPI == 4 && isV) ? bias2[col - 1024] : bias[col];
        #pragma unroll
        for (int mf = 0; mf < 4; mf++) {
            const int rbase = row0 + mf * 16 + g * 4;
            #pragma unroll
            for (int r = 0; r < 4; r++) {
                const int row = rbase + r;
                const float v = acc[mf][nf][r] + bv;
                if constexpr (EPI == 0) {
                    ((unsigned short*)outp)[(size_t)row * N + col] = f2bf(v * oscale);
                } else if constexpr (EPI == 1) {
                    const int bI = row >> 10, lk = row & 1023, hh = col >> 6, dd = col & 63;
                    ((unsigned short*)outp)[((size_t)(bI * 16 + hh) * 64 + dd) * 1024 + vperm(lk)] = f2bf(v);
                } else if constexpr (EPI == 2) {
                    ((unsigned short*)outp)[(size_t)row * N + col] = f2bf(v > 0.f ? v : 0.f);
                } else if constexpr (EPI == 3) {
                    ((float*)outp)[(size_t)row * N + col] = resid[(size_t)row * N + col] + v;
                } else {  // EPI == 4: fused K/V projection, N==2048
                    if (!isV) {
                        ((unsigned short*)outp)[(size_t)row * 1024 + col] = f2bf(v);
                    } else {
                        const int cc = col - 1024;
                        const int bI = row >> 10, lk = row & 1023, hh = cc >> 6, dd = cc & 63;
                        ((unsigned short*)outp2)[((size_t)(bI * 16 + hh) * 64 + dd) * 1024 + vperm(lk)] = f2bf(v);
                    }
                }
            }
        }
    }
}

// ---------------- GEMM body (m97 + T1 swizzle + T3 2-phase dbuf; r11-proven)
template<int EPI, int BN, int PF>
__device__ __forceinline__ void gemm_body(
    unsigned short* S,
    const unsigned short* __restrict__ A, const unsigned short* __restrict__ Bt,
    const float* __restrict__ bias, const float* __restrict__ bias2,
    void* __restrict__ outp, void* __restrict__ outp2,
    const float* __restrict__ resid, float oscale, int M, int N, int K,
    int vbid, int vgrid)
{
    constexpr int NF = BN / 32;                 // frags per wave in N
    constexpr int LDSH = (128 + BN) * 32;       // elems per 32-k slot (A then B)
    const int tid = threadIdx.x;
    const int lane = tid & 63, wave = tid >> 6;
    const int g = lane >> 4, q16 = lane & 15;
    const int wm = wave >> 1, wn = wave & 1;
    const int nb = N / BN;
    const int cpx = vgrid >> 3;
    const int swz = (vbid & 7) * cpx + (vbid >> 3);
    const int bm = swz / nb, bn = swz % nb;

    const unsigned short* aSrc = A  + (size_t)(bm * 128 + (tid >> 2)) * K + (tid & 3) * 8;
    const unsigned short* bSrc = Bt + (size_t)(bn * BN  + (tid >> 2)) * K + (tid & 3) * 8;
    const size_t rowStep = (size_t)64 * K;

    f32x4 acc[4][NF] = {};

    auto STAGE = [&](int slot, int kt) {
        unsigned short* aDst = &S[slot * LDSH] + wave * 512;       // wave-uniform base
        unsigned short* bDst = &S[slot * LDSH + 4096] + wave * 512;
        __builtin_amdgcn_global_load_lds((const AS1 unsigned int*)(aSrc + kt),           (AS3 unsigned int*)aDst,          16, 0, 0);
        __builtin_amdgcn_global_load_lds((const AS1 unsigned int*)(aSrc + rowStep + kt), (AS3 unsigned int*)(aDst + 2048), 16, 0, 0);
        __builtin_amdgcn_global_load_lds((const AS1 unsigned int*)(bSrc + kt),           (AS3 unsigned int*)bDst,          16, 0, 0);
        if constexpr (BN == 128)
            __builtin_amdgcn_global_load_lds((const AS1 unsigned int*)(bSrc + rowStep + kt), (AS3 unsigned int*)(bDst + 2048), 16, 0, 0);
    };
    auto COMPUTE = [&](int slot) {
        const unsigned short* As = &S[slot * LDSH];
        const unsigned short* Bs = As + 4096;
        short8 af[4], bfr[NF];
        #pragma unroll
        for (int i = 0; i < 4; i++)  af[i]  = *(const short8*)(As + (wm * 64 + i * 16 + q16) * 32 + g * 8);
        #pragma unroll
        for (int i = 0; i < NF; i++) bfr[i] = *(const short8*)(Bs + (wn * (BN / 2) + i * 16 + q16) * 32 + g * 8);
        #pragma unroll
        for (int mf = 0; mf < 4; mf++)
            #pragma unroll
            for (int nf = 0; nf < NF; nf++)
                acc[mf][nf] = __builtin_amdgcn_mfma_f32_16x16x32_bf16(af[mf], bfr[nf], acc[mf][nf], 0, 0, 0);
    };

    #pragma unroll
    for (int i = 0; i < PF; i++) STAGE(i, i * 32);
    __syncthreads();                 // drain: slots [0,PF) ready
    int p = 0;
    #pragma unroll 1
    for (int kt = PF * 32; kt < K; kt += PF * 32) {
        #pragma unroll
        for (int i = 0; i < PF; i++) STAGE((p ^ 1) * PF + i, kt + i * 32);  // prefetch pair
        #pragma unroll
        for (int i = 0; i < PF; i++) COMPUTE(p * PF + i);
        __syncthreads();             // next slots ready; current free for overwrite
        p ^= 1;
    }
    #pragma unroll
    for (int i = 0; i < PF; i++) COMPUTE(p * PF + i);   // tail (no prefetch)

    gemm_epilogue<EPI, BN>(acc, bm, bn, wm, wn, g, q16, bias, bias2,
                           outp, outp2, resid, oscale, N);
}

template<int EPI, int BN, int PF>
__global__ __launch_bounds__(256) void gemm_single(
    const unsigned short* __restrict__ A, const unsigned short* __restrict__ Bt,
    const float* __restrict__ bias, const float* __restrict__ bias2,
    void* __restrict__ outp, void* __restrict__ outp2,
    const float* __restrict__ resid, float oscale, int M, int N, int K)
{
    __shared__ unsigned short S[2 * PF * (128 + BN) * 32];
    gemm_body<EPI, BN, PF>(S, A, Bt, bias, bias2, outp, outp2, resid, oscale,
                           M, N, K, blockIdx.x, gridDim.x);
}

// -------- GEMM 3-buffer ring: stage-early, counted vmcnt, ONE non-draining
// s_barrier per pair (T4). Proven r15 (correct, clean FETCH). At BN=128 the
// wave tile is 64x64: 1.5x fewer ds_read_b128 per output than BN=64 — the
// LDS-instruction-throughput binder identified in r15's post-mortem.
template<int EPI, int BN, int PF>
__global__ __launch_bounds__(256) void gemm_ring3(
    const unsigned short* __restrict__ A, const unsigned short* __restrict__ Bt,
    const float* __restrict__ bias, const float* __restrict__ bias2,
    void* __restrict__ outp, void* __restrict__ outp2,
    const float* __restrict__ resid, float oscale, int M, int N, int K)
{
    constexpr int NF = BN / 32;
    constexpr int LDSH = (128 + BN) * 32;
    constexpr int LPP = PF * (BN == 128 ? 4 : 3);   // gload_lds per pair per wave
    __shared__ unsigned short S[3 * PF * LDSH];     // 3 pairs (96 KB @ BN=128)
    const int tid = threadIdx.x;
    const int lane = tid & 63, wave = tid >> 6;
    const int g = lane >> 4, q16 = lane & 15;
    const int wm = wave >> 1, wn = wave & 1;
    const int nb = N / BN;
    const int cpx = gridDim.x >> 3;
    const int swz = (blockIdx.x & 7) * cpx + (blockIdx.x >> 3);
    const int bm = swz / nb, bn = swz % nb;

    const unsigned short* aSrc = A  + (size_t)(bm * 128 + (tid >> 2)) * K + (tid & 3) * 8;
    const unsigned short* bSrc = Bt + (size_t)(bn * BN  + (tid >> 2)) * K + (tid & 3) * 8;
    const size_t rowStep = (size_t)64 * K;

    f32x4 acc[4][NF] = {};

    auto STAGEPAIR = [&](int pair, int t) {
        #pragma unroll
        for (int i = 0; i < PF; i++) {
            const int kt = t * PF * 32 + i * 32;
            unsigned short* aDst = &S[(pair * PF + i) * LDSH] + wave * 512;
            unsigned short* bDst = &S[(pair * PF + i) * LDSH + 4096] + wave * 512;
            __builtin_amdgcn_global_load_lds((const AS1 unsigned int*)(aSrc + kt),           (AS3 unsigned int*)aDst,          16, 0, 0);
            __builtin_amdgcn_global_load_lds((const AS1 unsigned int*)(aSrc + rowStep + kt), (AS3 unsigned int*)(aDst + 2048), 16, 0, 0);
            __builtin_amdgcn_global_load_lds((const AS1 unsigned int*)(bSrc + kt),           (AS3 unsigned int*)bDst,          16, 0, 0);
            if constexpr (BN == 128)
                __builtin_amdgcn_global_load_lds((const AS1 unsigned int*)(bSrc + rowStep + kt), (AS3 unsigned int*)(bDst + 2048), 16, 0, 0);
        }
    };
    auto COMPUTEPAIR = [&](int pair) {
        #pragma unroll
        for (int s = 0; s < PF; s++) {
            const unsigned short* As = &S[(pair * PF + s) * LDSH];
            const unsigned short* Bs = As + 4096;
            short8 af[4], bfr[NF];
            #pragma unroll
            for (int i = 0; i < 4; i++)  af[i]  = *(const short8*)(As + (wm * 64 + i * 16 + q16) * 32 + g * 8);
            #pragma unroll
            for (int i = 0; i < NF; i++) bfr[i] = *(const short8*)(Bs + (wn * (BN / 2) + i * 16 + q16) * 32 + g * 8);
            #pragma unroll
            for (int mf = 0; mf < 4; mf++)
                #pragma unroll
                for (int nf = 0; nf < NF; nf++)
                    acc[mf][nf] = __builtin_amdgcn_mfma_f32_16x16x32_bf16(af[mf], bfr[nf], acc[mf][nf], 0, 0, 0);
        }
    };

    const int NT = K / (PF * 32);           // >= 3 for all ring3 launches
    STAGEPAIR(0, 0);
    STAGEPAIR(1, 1);
    asm volatile("s_waitcnt vmcnt(%0)" :: "n"(LPP) : "memory");   // T0 done
    __builtin_amdgcn_s_barrier();                                  // T0 visible
    #pragma unroll 1
    for (int t = 0; t < NT; ++t) {
        if (t + 2 < NT) STAGEPAIR((t + 2) % 3, t + 2);   // overwrite pair read at t-1
        COMPUTEPAIR(t % 3);                               // T_t done+visible
        if (t + 1 < NT) asm volatile("s_waitcnt vmcnt(%0)" :: "n"(LPP) : "memory");
        else            asm volatile("s_waitcnt vmcnt(0)" ::: "memory");
        __builtin_amdgcn_s_barrier();                     // T_{t+1} visible; readers done
    }

    gemm_epilogue<EPI, BN>(acc, bm, bn, wm, wn, g, q16, bias, bias2,
                           outp, outp2, resid, oscale, N);
}

// ------------- fused Q + KV projections (independent; one 1024-block launch)
__global__ __launch_bounds__(256) void qkv_fused(
    const unsigned short* __restrict__ XA, const unsigned short* __restrict__ WQT,
    const float* __restrict__ bq,
    const unsigned short* __restrict__ M16, const unsigned short* __restrict__ WKT,
    const float* __restrict__ bk, const float* __restrict__ bv,
    unsigned short* __restrict__ Qb, unsigned short* __restrict__ Kb,
    unsigned short* __restrict__ Vt, float qscale)
{
    __shared__ unsigned short S[2 * 2 * 256 * 32];   // 64 KB (max of the two shapes)
    if (blockIdx.x < 512)
        gemm_body<0, 64, 2>(S, XA, WQT, bq, nullptr, Qb, nullptr, nullptr,
                            qscale, 4096, 1024, 1024, blockIdx.x, 512);
    else
        gemm_body<4, 128, 2>(S, M16, WKT, bk, bv, Kb, Vt, nullptr,
                             1.0f, 4096, 2048, 1024, blockIdx.x - 512, 512);
}

// ------------------------------------------------------------- attention PV
__global__ __launch_bounds__(256) void att_pv(
    const unsigned short* __restrict__ Q, const unsigned short* __restrict__ Kb,
    const unsigned short* __restrict__ Vt, unsigned short* __restrict__ O,
    float* __restrict__ LINV)
{
    __shared__ unsigned short Ks[2][2048];   // [32k][64d], swizzled 16B slots
    __shared__ unsigned short Vs[2][2048];   // [64d][32k], swizzled 16B slots
    const int tid = threadIdx.x, lane = tid & 63, wave = tid >> 6;
    const int g = lane >> 4, q16 = lane & 15;
    const int bh = blockIdx.x & 63;     // stride-64 blocks share (b,h) -> same XCD
    const int qt = blockIdx.x >> 6;     // 0..7
    const int b = bh >> 4, h = bh & 15;
    const int qbase = qt * 128 + wave * 32;

    const int rowK = wave * 8 + (lane >> 3);          // k-row within chunk
    const int cK   = (lane & 7) ^ (rowK & 7);         // swizzled 16B slot
    const int rowV = wave * 16 + (lane >> 2);         // d-row
    const int cV   = (lane & 3) ^ (rowV & 3);
    const unsigned short* kSrc = Kb + ((size_t)(b * 1024 + rowK)) * 1024 + h * 64 + cK * 8;
    const unsigned short* vSrc = Vt + ((size_t)(bh * 64 + rowV)) * 1024 + cV * 8;

    short8 qf[2][2];
    #pragma unroll
    for (int nf = 0; nf < 2; nf++)
        #pragma unroll
        for (int ds = 0; ds < 2; ds++)
            qf[nf][ds] = *(const short8*)(Q + (size_t)(b * 1024 + qbase + nf * 16 + q16) * 1024 + h * 64 + ds * 32 + g * 8);

    f32x4 oacc[4][2] = {};
    float lsum[2] = {0.f, 0.f};

    auto STAGE = [&](int buf, int kc) {
        __builtin_amdgcn_global_load_lds((const AS1 unsigned int*)(kSrc + (size_t)kc * 1024),
                                         (AS3 unsigned int*)(&Ks[buf][0] + wave * 512), 16, 0, 0);
        __builtin_amdgcn_global_load_lds((const AS1 unsigned int*)(vSrc + kc),
                                         (AS3 unsigned int*)(&Vs[buf][0] + wave * 512), 16, 0, 0);
    };
    auto BODY = [&](int buf) {
        short8 kf[2][2], vf[4];
        #pragma unroll
        for (int kt = 0; kt < 2; kt++)
            #pragma unroll
            for (int ds = 0; ds < 2; ds++)
                kf[kt][ds] = *(const short8*)(&Ks[buf][0] + (kt * 16 + q16) * 64 + ((ds * 4 + g) ^ (q16 & 7)) * 8);
        #pragma unroll
        for (int mf = 0; mf < 4; mf++)
            vf[mf] = *(const short8*)(&Vs[buf][0] + (mf * 16 + q16) * 32 + (g ^ (q16 & 3)) * 8);
        f32x4 sacc[2][2] = {};
        #pragma unroll
        for (int kt = 0; kt < 2; kt++)
            #pragma unroll
            for (int nf = 0; nf < 2; nf++) {
                sacc[kt][nf] = __builtin_amdgcn_mfma_f32_16x16x32_bf16(kf[kt][0], qf[nf][0], sacc[kt][nf], 0, 0, 0);
                sacc[kt][nf] = __builtin_amdgcn_mfma_f32_16x16x32_bf16(kf[kt][1], qf[nf][1], sacc[kt][nf], 0, 0, 0);
            }
        float ps[2][2][4];
        #pragma unroll
        for (int kt = 0; kt < 2; kt++)
            #pragma unroll
            for (int nf = 0; nf < 2; nf++)
                #pragma unroll
                for (int r = 0; r < 4; r++)
                    ps[kt][nf][r] = exp2_hw(sacc[kt][nf][r]);
        #pragma unroll
        for (int nf = 0; nf < 2; nf++)
            lsum[nf] += ps[0][nf][0] + ps[0][nf][1] + ps[0][nf][2] + ps[0][nf][3]
                      + ps[1][nf][0] + ps[1][nf][1] + ps[1][nf][2] + ps[1][nf][3];
        short8 pbf[2];
        #pragma unroll
        for (int nf = 0; nf < 2; nf++) {
            pbf[nf][0] = (short)f2bf(ps[0][nf][0]);
            pbf[nf][1] = (short)f2bf(ps[0][nf][1]);
            pbf[nf][2] = (short)f2bf(ps[0][nf][2]);
            pbf[nf][3] = (short)f2bf(ps[0][nf][3]);
            pbf[nf][4] = (short)f2bf(ps[1][nf][0]);
            pbf[nf][5] = (short)f2bf(ps[1][nf][1]);
            pbf[nf][6] = (short)f2bf(ps[1][nf][2]);
            pbf[nf][7] = (short)f2bf(ps[1][nf][3]);
        }
        #pragma unroll
        for (int mf = 0; mf < 4; mf++)
            #pragma unroll
            for (int nf = 0; nf < 2; nf++)
                oacc[mf][nf] = __builtin_amdgcn_mfma_f32_16x16x32_bf16(vf[mf], pbf[nf], oacc[mf][nf], 0, 0, 0);
    };

    STAGE(0, 0);
    __syncthreads();                 // buf0 staged
    int buf = 0;
    #pragma unroll 1
    for (int kc = 0; kc < 1024; kc += 32) {
        if (kc + 32 < 1024) STAGE(buf ^ 1, kc + 32);   // flies under BODY
        BODY(buf);
        __syncthreads();             // next buf ready; cur free for overwrite
        buf ^= 1;
    }
    #pragma unroll
    for (int nf = 0; nf < 2; nf++) {               // deferred cross-lane reduce
        lsum[nf] += __shfl_xor(lsum[nf], 16);
        lsum[nf] += __shfl_xor(lsum[nf], 32);
    }

    #pragma unroll
    for (int nf = 0; nf < 2; nf++) {
        const float inv = 1.0f / lsum[nf];
        if (g == 0) LINV[(size_t)bh * 1024 + qbase + nf * 16 + q16] = inv;
        #pragma unroll
        for (int mf = 0; mf < 4; mf++) {
            u16x4 o;
            #pragma unroll
            for (int r = 0; r < 4; r++) o[r] = f2bf(oacc[mf][nf][r] * inv);
            *(u16x4*)(O + (size_t)(b * 1024 + qbase + nf * 16 + q16) * 1024 + h * 64 + mf * 16 + g * 4) = o;
        }
    }
}

// ------------------------------------------------- head-averaged attn output
__global__ __launch_bounds__(256) void att_mean(
    const unsigned short* __restrict__ Q, const unsigned short* __restrict__ Kb,
    const float* __restrict__ LINV, float* __restrict__ out1)
{
    __shared__ unsigned short Qs[2][2048];   // [32q][64d], swizzled 16B slots
    const int tid = threadIdx.x;
    const int lane = tid & 63, wave = tid >> 6;
    const int g = lane >> 4, q16 = lane & 15;
    const int kb = blockIdx.x & 7;
    const int qb = (blockIdx.x >> 3) & 31;
    const int b = blockIdx.x >> 8;
    const int qbase = qb * 32;
    const int kbase = kb * 128 + wave * 32;

    const int rowQ = wave * 8 + (lane >> 3);
    const int cQ   = (lane & 7) ^ (rowQ & 7);
    const unsigned short* qSrc = Q + (size_t)(b * 1024 + qbase + rowQ) * 1024 + cQ * 8;

    f32x4 facc[2][2] = {};

    auto STAGE = [&](int buf, int h) {
        __builtin_amdgcn_global_load_lds((const AS1 unsigned int*)(qSrc + h * 64),
                                         (AS3 unsigned int*)(&Qs[buf][0] + wave * 512), 16, 0, 0);
    };
    auto LOADK = [&](short8 (&kf)[2][2], f32x4 (&li)[2], int h) {
        #pragma unroll
        for (int nf = 0; nf < 2; nf++)
            #pragma unroll
            for (int ds = 0; ds < 2; ds++)
                kf[nf][ds] = *(const short8*)(Kb + (size_t)(b * 1024 + kbase + nf * 16 + q16) * 1024 + h * 64 + ds * 32 + g * 8);
        const float* lp = LINV + (size_t)(b * 16 + h) * 1024 + qbase;
        #pragma unroll
        for (int mf = 0; mf < 2; mf++)
            li[mf] = *(const f32x4*)(lp + mf * 16 + g * 4);
    };
    auto COMP = [&](int buf, short8 (&kf)[2][2], f32x4 (&li)[2]) {
        short8 qfr[2][2];
        #pragma unroll
        for (int mf = 0; mf < 2; mf++)
            #pragma unroll
            for (int ds = 0; ds < 2; ds++)
                qfr[mf][ds] = *(const short8*)(&Qs[buf][0] + (mf * 16 + q16) * 64 + ((ds * 4 + g) ^ (q16 & 7)) * 8);
        #pragma unroll
        for (int nf = 0; nf < 2; nf++) {
            f32x4 sacc[2] = {};
            #pragma unroll
            for (int mf = 0; mf < 2; mf++) {
                sacc[mf] = __builtin_amdgcn_mfma_f32_16x16x32_bf16(qfr[mf][0], kf[nf][0], sacc[mf], 0, 0, 0);
                sacc[mf] = __builtin_amdgcn_mfma_f32_16x16x32_bf16(qfr[mf][1], kf[nf][1], sacc[mf], 0, 0, 0);
            }
            #pragma unroll
            for (int mf = 0; mf < 2; mf++)
                #pragma unroll
                for (int r = 0; r < 4; r++)
                    facc[mf][nf][r] = fmaf(exp2_hw(sacc[mf][r]), li[mf][r], facc[mf][nf][r]);
        }
    };

    short8 kA[2][2], kB[2][2];
    f32x4 liA[2], liB[2];
    STAGE(0, 0); LOADK(kA, liA, 0);
    __syncthreads();                     // buf0 staged
    #pragma unroll 1
    for (int h = 0; h < 16; h += 2) {
        STAGE(1, h + 1); LOADK(kB, liB, h + 1);     // fly under COMP(buf0)
        COMP(0, kA, liA);
        __syncthreads();                 // buf1 staged; buf0 reads done
        if (h + 2 < 16) { STAGE(0, h + 2); LOADK(kA, liA, h + 2); }
        COMP(1, kB, liB);
        __syncthreads();                 // buf0 staged; buf1 reads done
    }

    #pragma unroll
    for (int mf = 0; mf < 2; mf++)
        #pragma unroll
        for (int nf = 0; nf < 2; nf++)
            #pragma unroll
            for (int r = 0; r < 4; r++)
                out1[(size_t)(b * 1024 + qbase + mf * 16 + g * 4 + r) * 1024 + kbase + nf * 16 + q16]
                    = facc[mf][nf][r] * 0.0625f;
}

// ---------------------------------------------------------------- launcher
extern "C" void kernel_launch(void* const* d_in, const int* in_sizes, int n_in,
                              void* d_out, int out_size, void* d_ws, size_t ws_size,
                              hipStream_t stream)
{
    (void)in_sizes; (void)n_in; (void)out_size; (void)ws_size;
    const float* tgt  = (const float*)d_in[0];
    const float* mem  = (const float*)d_in[1];
    const float* ln1g = (const float*)d_in[2];
    const float* ln1b = (const float*)d_in[3];
    const float* wq   = (const float*)d_in[4];
    const float* bq   = (const float*)d_in[5];
    const float* wk   = (const float*)d_in[6];
    const float* bk   = (const float*)d_in[7];
    const float* wv   = (const float*)d_in[8];
    const float* bv   = (const float*)d_in[9];
    const float* wo   = (const float*)d_in[10];
    const float* bo   = (const float*)d_in[11];
    const float* ln3g = (const float*)d_in[12];
    const float* ln3b = (const float*)d_in[13];
    const float* w1   = (const float*)d_in[14];
    const float* b1   = (const float*)d_in[15];
    const float* w2   = (const float*)d_in[16];
    const float* b2   = (const float*)d_in[17];

    char* ws = (char*)d_ws;
    unsigned short* XA  = (unsigned short*)(ws);                  // 8 MB (t2, later t3)
    unsigned short* M16 = (unsigned short*)(ws + ((size_t)8  << 20));
    unsigned short* WQT = (unsigned short*)(ws + ((size_t)16 << 20));
    unsigned short* WKT = (unsigned short*)(ws + ((size_t)18 << 20)); // [WKT;WVT] = fused 2048xK
    unsigned short* WVT = (unsigned short*)(ws + ((size_t)20 << 20));
    unsigned short* WOT = (unsigned short*)(ws + ((size_t)22 << 20));
    unsigned short* W1T = (unsigned short*)(ws + ((size_t)24 << 20)); // 8 MB
    unsigned short* W2T = (unsigned short*)(ws + ((size_t)32 << 20)); // 8 MB
    unsigned short* Qb  = (unsigned short*)(ws + ((size_t)40 << 20));
    unsigned short* Kb  = (unsigned short*)(ws + ((size_t)48 << 20));
    unsigned short* Vt  = (unsigned short*)(ws + ((size_t)56 << 20));
    unsigned short* O16 = (unsigned short*)(ws + ((size_t)64 << 20));
    unsigned short* H16 = (unsigned short*)(ws + ((size_t)72 << 20)); // 32 MB
    float*          LNV = (float*)(ws + ((size_t)104 << 20));         // 256 KB
    float* xout = (float*)d_out;                       // x then x+ffn [4096][1024]
    float* attn = xout + (size_t)4 * 1024 * 1024;      // [4][1024][1024]

    const float QSCALE = 0.125f * 1.4426950408889634f;   // fold softmax scale + log2e into Q

    prep_fused<<<20480, 256, 0, stream>>>(tgt, ln1g, ln1b, XA, mem, M16,
                                          wq, wk, wv, wo, WQT, WKT, WVT, WOT,
                                          w1, W1T, w2, W2T);

    // fused Q (prescaled, EPI0/BN64) + KV (EPI4/BN128) projections, grid 1024
    qkv_fused<<<1024, 256, 0, stream>>>(XA, WQT, bq, M16, WKT, bk, bv, Qb, Kb, Vt, QSCALE);

    att_pv<<<512, 256, 0, stream>>>(Qb, Kb, Vt, O16, LNV);
    att_mean<<<1024, 256, 0, stream>>>(Qb, Kb, LNV, attn);

    // WO: N=1024, BN=64, PF=2 -> grid 512 (writes xout = tgt + attn*WO)
    gemm_single<3, 64, 2><<<32 * 16, 256, 0, stream>>>(O16, WOT, bo, nullptr, xout, nullptr, tgt, 1.0f, 4096, 1024, 1024);
    ln_to_bf16<<<4096, 256, 0, stream>>>(xout, ln3g, ln3b, XA);
    // FFN1: N=4096, BN=128, PF=2 -> grid 1024
    gemm_single<2, 128, 2><<<32 * 32, 256, 0, stream>>>(XA, W1T, b1, nullptr, H16, nullptr, nullptr, 1.0f, 4096, 4096, 1024);
    // FFN2: ring3 @ BN=128 (64x64 wave tile, 1.5x fewer ds_reads), grid 256
    gemm_ring3<3, 128, 2><<<32 * 8, 256, 0, stream>>>(H16, W2T, b2, nullptr, xout, nullptr, xout, 1.0f, 4096, 1024, 4096);
}

// Round 17
// 257.200 us; speedup vs baseline: 1.0158x; 1.0132x over previous
//
#include <hip/hip_runtime.h>
#include <hip/hip_bf16.h>

using short8 = __attribute__((ext_vector_type(8))) short;          // 8 bf16 (4 VGPR)
using f32x4  = __attribute__((ext_vector_type(4))) float;          // MFMA acc
using u16x4  = __attribute__((ext_vector_type(4))) unsigned short; // 8B bf16 store

#define AS1 __attribute__((address_space(1)))
#define AS3 __attribute__((address_space(3)))

__device__ __forceinline__ unsigned short f2bf(float f) {
    __hip_bfloat16 h = __float2bfloat16(f);    // RNE
    return __builtin_bit_cast(unsigned short, h);
}

__device__ __forceinline__ float exp2_hw(float x) {
    float r;
    asm("v_exp_f32 %0, %1" : "=v"(r) : "v"(x));   // D = 2^S0
    return r;
}

// pi-permutation of key k within a 32-key chunk: position of key k in the
// slot order {4g..4g+3, 16+4g..19+4g} for g = 0..3 (slot = g*8+j).
__device__ __forceinline__ int vperm(int lk) {
    return (lk & ~31) | (((lk >> 2) & 3) * 8) | (((lk >> 4) & 1) * 4) | (lk & 3);
}

// ---------------------------------------------------------------- LN -> bf16
__global__ __launch_bounds__(256) void ln_to_bf16(
    const float* __restrict__ X, const float* __restrict__ gw,
    const float* __restrict__ bw, unsigned short* __restrict__ Y)
{
    const int row = blockIdx.x;
    const int tid = threadIdx.x;
    const float4 v = *(const float4*)(X + (size_t)row * 1024 + tid * 4);
    float s  = v.x + v.y + v.z + v.w;
    float s2 = v.x*v.x + v.y*v.y + v.z*v.z + v.w*v.w;
    #pragma unroll
    for (int off = 1; off < 64; off <<= 1) {
        s  += __shfl_xor(s,  off);
        s2 += __shfl_xor(s2, off);
    }
    __shared__ float rs[4], rq[4];
    if ((tid & 63) == 0) { rs[tid >> 6] = s; rq[tid >> 6] = s2; }
    __syncthreads();
    s  = rs[0] + rs[1] + rs[2] + rs[3];
    s2 = rq[0] + rq[1] + rq[2] + rq[3];
    const float mean = s * (1.f / 1024.f);
    const float var  = s2 * (1.f / 1024.f) - mean * mean;
    const float rstd = rsqrtf(var + 1e-5f);
    const float4 gv = *(const float4*)(gw + tid * 4);
    const float4 bv = *(const float4*)(bw + tid * 4);
    u16x4 o;
    o[0] = f2bf((v.x - mean) * rstd * gv.x + bv.x);
    o[1] = f2bf((v.y - mean) * rstd * gv.y + bv.y);
    o[2] = f2bf((v.z - mean) * rstd * gv.z + bv.z);
    o[3] = f2bf((v.w - mean) * rstd * gv.w + bv.w);
    *(u16x4*)(Y + (size_t)row * 1024 + tid * 4) = o;
}

// -------------------- fused preprocessing: ln1 | cast(mem) | 6 transposes
__global__ __launch_bounds__(256) void prep_fused(
    const float* __restrict__ tgt, const float* __restrict__ ln1g,
    const float* __restrict__ ln1b, unsigned short* __restrict__ XA,
    const float* __restrict__ mem, unsigned short* __restrict__ M16,
    const float* __restrict__ wq, const float* __restrict__ wk,
    const float* __restrict__ wv, const float* __restrict__ wo,
    unsigned short* __restrict__ WQT, unsigned short* __restrict__ WKT,
    unsigned short* __restrict__ WVT, unsigned short* __restrict__ WOT,
    const float* __restrict__ w1, unsigned short* __restrict__ W1T,
    const float* __restrict__ w2, unsigned short* __restrict__ W2T)
{
    __shared__ float t[32][33];
    __shared__ float rs[4], rq[4];
    const int bid = blockIdx.x;
    const int tid = threadIdx.x;
    if (bid < 4096) {                                    // ---- LN(tgt) -> XA
        const int row = bid;
        const float4 v = *(const float4*)(tgt + (size_t)row * 1024 + tid * 4);
        float s  = v.x + v.y + v.z + v.w;
        float s2 = v.x*v.x + v.y*v.y + v.z*v.z + v.w*v.w;
        #pragma unroll
        for (int off = 1; off < 64; off <<= 1) {
            s  += __shfl_xor(s,  off);
            s2 += __shfl_xor(s2, off);
        }
        if ((tid & 63) == 0) { rs[tid >> 6] = s; rq[tid >> 6] = s2; }
        __syncthreads();
        s  = rs[0] + rs[1] + rs[2] + rs[3];
        s2 = rq[0] + rq[1] + rq[2] + rq[3];
        const float mean = s * (1.f / 1024.f);
        const float var  = s2 * (1.f / 1024.f) - mean * mean;
        const float rstd = rsqrtf(var + 1e-5f);
        const float4 gv = *(const float4*)(ln1g + tid * 4);
        const float4 bv = *(const float4*)(ln1b + tid * 4);
        u16x4 o;
        o[0] = f2bf((v.x - mean) * rstd * gv.x + bv.x);
        o[1] = f2bf((v.y - mean) * rstd * gv.y + bv.y);
        o[2] = f2bf((v.z - mean) * rstd * gv.z + bv.z);
        o[3] = f2bf((v.w - mean) * rstd * gv.w + bv.w);
        *(u16x4*)(XA + (size_t)row * 1024 + tid * 4) = o;
    } else if (bid < 8192) {                             // ---- cast mem -> M16
        const int i = (bid - 4096) * 256 + tid;          // n4 = 1048576 exact
        float4 v = ((const float4*)mem)[i];
        u16x4 o = { f2bf(v.x), f2bf(v.y), f2bf(v.z), f2bf(v.w) };
        ((u16x4*)M16)[i] = o;
    } else {                                             // ---- transposes
        const float* W; unsigned short* Wt; int kb, nb, K;
        if (bid < 12288) {
            const int idx2 = bid - 8192;
            const int which = idx2 >> 10;
            W  = which == 0 ? wq : which == 1 ? wk : which == 2 ? wv : wo;
            Wt = which == 0 ? WQT : which == 1 ? WKT : which == 2 ? WVT : WOT;
            const int idx = idx2 & 1023;
            kb = idx & 31; nb = idx >> 5; K = 1024;
            const int c = tid & 31, r0 = tid >> 5;
            #pragma unroll
            for (int i = 0; i < 4; i++)
                t[r0 + i * 8][c] = W[(size_t)(kb * 32 + r0 + i * 8) * 1024 + nb * 32 + c];
            __syncthreads();
            #pragma unroll
            for (int i = 0; i < 4; i++)
                Wt[(size_t)(nb * 32 + r0 + i * 8) * K + kb * 32 + c] = f2bf(t[c][r0 + i * 8]);
        } else {
            int N;
            if (bid < 16384) { const int idx = bid - 12288; kb = idx % 32;  nb = idx / 32;  K = 1024; N = 4096; W = w1; Wt = W1T; }
            else             { const int idx = bid - 16384; kb = idx % 128; nb = idx / 128; K = 4096; N = 1024; W = w2; Wt = W2T; }
            const int c = tid & 31, r0 = tid >> 5;
            #pragma unroll
            for (int i = 0; i < 4; i++)
                t[r0 + i * 8][c] = W[(size_t)(kb * 32 + r0 + i * 8) * N + nb * 32 + c];
            __syncthreads();
            #pragma unroll
            for (int i = 0; i < 4; i++)
                Wt[(size_t)(nb * 32 + r0 + i * 8) * K + kb * 32 + c] = f2bf(t[c][r0 + i * 8]);
        }
    }
}

// ------------------------------------------- shared GEMM epilogue (EPI dispatch)
template<int EPI, int BN>
__device__ __forceinline__ void gemm_epilogue(
    f32x4 (&acc)[4][BN / 32], int bm, int bn, int wm, int wn, int g, int q16,
    const float* __restrict__ bias, const float* __restrict__ bias2,
    void* __restrict__ outp, void* __restrict__ outp2,
    const float* __restrict__ resid, float oscale, int N)
{
    constexpr int NF = BN / 32;
    const int row0 = bm * 128 + wm * 64;
    const int col0 = bn * BN + wn * (BN / 2);
    const bool isV = (EPI == 4) && (bn * BN >= 1024);
    #pragma unroll
    for (int nf = 0; nf < NF; nf++) {
        const int col = col0 + nf * 16 + q16;
        const float bv = (EPI == 4 && isV) ? bias2[col - 1024] : bias[col];
        #pragma unroll
        for (int mf = 0; mf < 4; mf++) {
            const int rbase = row0 + mf * 16 + g * 4;
            #pragma unroll
            for (int r = 0; r < 4; r++) {
                const int row = rbase + r;
                const float v = acc[mf][nf][r] + bv;
                if constexpr (EPI == 0) {
                    ((unsigned short*)outp)[(size_t)row * N + col] = f2bf(v * oscale);
                } else if constexpr (EPI == 1) {
                    const int bI = row >> 10, lk = row & 1023, hh = col >> 6, dd = col & 63;
                    ((unsigned short*)outp)[((size_t)(bI * 16 + hh) * 64 + dd) * 1024 + vperm(lk)] = f2bf(v);
                } else if constexpr (EPI == 2) {
                    ((unsigned short*)outp)[(size_t)row * N + col] = f2bf(v > 0.f ? v : 0.f);
                } else if constexpr (EPI == 3) {
                    ((float*)outp)[(size_t)row * N + col] = resid[(size_t)row * N + col] + v;
                } else {  // EPI == 4: fused K/V projection, N==2048
                    if (!isV) {
                        ((unsigned short*)outp)[(size_t)row * 1024 + col] = f2bf(v);
                    } else {
                        const int cc = col - 1024;
                        const int bI = row >> 10, lk = row & 1023, hh = cc >> 6, dd = cc & 63;
                        ((unsigned short*)outp2)[((size_t)(bI * 16 + hh) * 64 + dd) * 1024 + vperm(lk)] = f2bf(v);
                    }
                }
            }
        }
    }
}

// ---------------- GEMM body (m97 + T1 swizzle + T3 2-phase dbuf; r11-proven)
template<int EPI, int BN, int PF>
__device__ __forceinline__ void gemm_body(
    unsigned short* S,
    const unsigned short* __restrict__ A, const unsigned short* __restrict__ Bt,
    const float* __restrict__ bias, const float* __restrict__ bias2,
    void* __restrict__ outp, void* __restrict__ outp2,
    const float* __restrict__ resid, float oscale, int M, int N, int K,
    int vbid, int vgrid)
{
    constexpr int NF = BN / 32;                 // frags per wave in N
    constexpr int LDSH = (128 + BN) * 32;       // elems per 32-k slot (A then B)
    const int tid = threadIdx.x;
    const int lane = tid & 63, wave = tid >> 6;
    const int g = lane >> 4, q16 = lane & 15;
    const int wm = wave >> 1, wn = wave & 1;
    const int nb = N / BN;
    const int cpx = vgrid >> 3;
    const int swz = (vbid & 7) * cpx + (vbid >> 3);
    const int bm = swz / nb, bn = swz % nb;

    const unsigned short* aSrc = A  + (size_t)(bm * 128 + (tid >> 2)) * K + (tid & 3) * 8;
    const unsigned short* bSrc = Bt + (size_t)(bn * BN  + (tid >> 2)) * K + (tid & 3) * 8;
    const size_t rowStep = (size_t)64 * K;

    f32x4 acc[4][NF] = {};

    auto STAGE = [&](int slot, int kt) {
        unsigned short* aDst = &S[slot * LDSH] + wave * 512;       // wave-uniform base
        unsigned short* bDst = &S[slot * LDSH + 4096] + wave * 512;
        __builtin_amdgcn_global_load_lds((const AS1 unsigned int*)(aSrc + kt),           (AS3 unsigned int*)aDst,          16, 0, 0);
        __builtin_amdgcn_global_load_lds((const AS1 unsigned int*)(aSrc + rowStep + kt), (AS3 unsigned int*)(aDst + 2048), 16, 0, 0);
        __builtin_amdgcn_global_load_lds((const AS1 unsigned int*)(bSrc + kt),           (AS3 unsigned int*)bDst,          16, 0, 0);
        if constexpr (BN == 128)
            __builtin_amdgcn_global_load_lds((const AS1 unsigned int*)(bSrc + rowStep + kt), (AS3 unsigned int*)(bDst + 2048), 16, 0, 0);
    };
    auto COMPUTE = [&](int slot) {
        const unsigned short* As = &S[slot * LDSH];
        const unsigned short* Bs = As + 4096;
        short8 af[4], bfr[NF];
        #pragma unroll
        for (int i = 0; i < 4; i++)  af[i]  = *(const short8*)(As + (wm * 64 + i * 16 + q16) * 32 + g * 8);
        #pragma unroll
        for (int i = 0; i < NF; i++) bfr[i] = *(const short8*)(Bs + (wn * (BN / 2) + i * 16 + q16) * 32 + g * 8);
        #pragma unroll
        for (int mf = 0; mf < 4; mf++)
            #pragma unroll
            for (int nf = 0; nf < NF; nf++)
                acc[mf][nf] = __builtin_amdgcn_mfma_f32_16x16x32_bf16(af[mf], bfr[nf], acc[mf][nf], 0, 0, 0);
    };

    #pragma unroll
    for (int i = 0; i < PF; i++) STAGE(i, i * 32);
    __syncthreads();                 // drain: slots [0,PF) ready
    int p = 0;
    #pragma unroll 1
    for (int kt = PF * 32; kt < K; kt += PF * 32) {
        #pragma unroll
        for (int i = 0; i < PF; i++) STAGE((p ^ 1) * PF + i, kt + i * 32);  // prefetch pair
        #pragma unroll
        for (int i = 0; i < PF; i++) COMPUTE(p * PF + i);
        __syncthreads();             // next slots ready; current free for overwrite
        p ^= 1;
    }
    #pragma unroll
    for (int i = 0; i < PF; i++) COMPUTE(p * PF + i);   // tail (no prefetch)

    gemm_epilogue<EPI, BN>(acc, bm, bn, wm, wn, g, q16, bias, bias2,
                           outp, outp2, resid, oscale, N);
}

template<int EPI, int BN, int PF>
__global__ __launch_bounds__(256) void gemm_single(
    const unsigned short* __restrict__ A, const unsigned short* __restrict__ Bt,
    const float* __restrict__ bias, const float* __restrict__ bias2,
    void* __restrict__ outp, void* __restrict__ outp2,
    const float* __restrict__ resid, float oscale, int M, int N, int K)
{
    __shared__ unsigned short S[2 * PF * (128 + BN) * 32];
    gemm_body<EPI, BN, PF>(S, A, Bt, bias, bias2, outp, outp2, resid, oscale,
                           M, N, K, blockIdx.x, gridDim.x);
}

// -------- GEMM 3-buffer ring (r15-proven @ BN=64): stage-early, counted
// vmcnt, ONE non-draining s_barrier per pair (T4).
template<int EPI, int BN, int PF>
__global__ __launch_bounds__(256) void gemm_ring3(
    const unsigned short* __restrict__ A, const unsigned short* __restrict__ Bt,
    const float* __restrict__ bias, const float* __restrict__ bias2,
    void* __restrict__ outp, void* __restrict__ outp2,
    const float* __restrict__ resid, float oscale, int M, int N, int K)
{
    constexpr int NF = BN / 32;
    constexpr int LDSH = (128 + BN) * 32;
    constexpr int LPP = PF * (BN == 128 ? 4 : 3);   // gload_lds per pair per wave
    __shared__ unsigned short S[3 * PF * LDSH];     // 3 pairs
    const int tid = threadIdx.x;
    const int lane = tid & 63, wave = tid >> 6;
    const int g = lane >> 4, q16 = lane & 15;
    const int wm = wave >> 1, wn = wave & 1;
    const int nb = N / BN;
    const int cpx = gridDim.x >> 3;
    const int swz = (blockIdx.x & 7) * cpx + (blockIdx.x >> 3);
    const int bm = swz / nb, bn = swz % nb;

    const unsigned short* aSrc = A  + (size_t)(bm * 128 + (tid >> 2)) * K + (tid & 3) * 8;
    const unsigned short* bSrc = Bt + (size_t)(bn * BN  + (tid >> 2)) * K + (tid & 3) * 8;
    const size_t rowStep = (size_t)64 * K;

    f32x4 acc[4][NF] = {};

    auto STAGEPAIR = [&](int pair, int t) {
        #pragma unroll
        for (int i = 0; i < PF; i++) {
            const int kt = t * PF * 32 + i * 32;
            unsigned short* aDst = &S[(pair * PF + i) * LDSH] + wave * 512;
            unsigned short* bDst = &S[(pair * PF + i) * LDSH + 4096] + wave * 512;
            __builtin_amdgcn_global_load_lds((const AS1 unsigned int*)(aSrc + kt),           (AS3 unsigned int*)aDst,          16, 0, 0);
            __builtin_amdgcn_global_load_lds((const AS1 unsigned int*)(aSrc + rowStep + kt), (AS3 unsigned int*)(aDst + 2048), 16, 0, 0);
            __builtin_amdgcn_global_load_lds((const AS1 unsigned int*)(bSrc + kt),           (AS3 unsigned int*)bDst,          16, 0, 0);
            if constexpr (BN == 128)
                __builtin_amdgcn_global_load_lds((const AS1 unsigned int*)(bSrc + rowStep + kt), (AS3 unsigned int*)(bDst + 2048), 16, 0, 0);
        }
    };
    auto COMPUTEPAIR = [&](int pair) {
        #pragma unroll
        for (int s = 0; s < PF; s++) {
            const unsigned short* As = &S[(pair * PF + s) * LDSH];
            const unsigned short* Bs = As + 4096;
            short8 af[4], bfr[NF];
            #pragma unroll
            for (int i = 0; i < 4; i++)  af[i]  = *(const short8*)(As + (wm * 64 + i * 16 + q16) * 32 + g * 8);
            #pragma unroll
            for (int i = 0; i < NF; i++) bfr[i] = *(const short8*)(Bs + (wn * (BN / 2) + i * 16 + q16) * 32 + g * 8);
            #pragma unroll
            for (int mf = 0; mf < 4; mf++)
                #pragma unroll
                for (int nf = 0; nf < NF; nf++)
                    acc[mf][nf] = __builtin_amdgcn_mfma_f32_16x16x32_bf16(af[mf], bfr[nf], acc[mf][nf], 0, 0, 0);
        }
    };

    const int NT = K / (PF * 32);           // >= 3 for all ring3 launches
    STAGEPAIR(0, 0);
    STAGEPAIR(1, 1);
    asm volatile("s_waitcnt vmcnt(%0)" :: "n"(LPP) : "memory");   // T0 done
    __builtin_amdgcn_s_barrier();                                  // T0 visible
    #pragma unroll 1
    for (int t = 0; t < NT; ++t) {
        if (t + 2 < NT) STAGEPAIR((t + 2) % 3, t + 2);   // overwrite pair read at t-1
        COMPUTEPAIR(t % 3);                               // T_t done+visible
        if (t + 1 < NT) asm volatile("s_waitcnt vmcnt(%0)" :: "n"(LPP) : "memory");
        else            asm volatile("s_waitcnt vmcnt(0)" ::: "memory");
        __builtin_amdgcn_s_barrier();                     // T_{t+1} visible; readers done
    }

    gemm_epilogue<EPI, BN>(acc, bm, bn, wm, wn, g, q16, bias, bias2,
                           outp, outp2, resid, oscale, N);
}

// ------------- fused Q + KV projections (independent; one 1024-block launch)
__global__ __launch_bounds__(256) void qkv_fused(
    const unsigned short* __restrict__ XA, const unsigned short* __restrict__ WQT,
    const float* __restrict__ bq,
    const unsigned short* __restrict__ M16, const unsigned short* __restrict__ WKT,
    const float* __restrict__ bk, const float* __restrict__ bv,
    unsigned short* __restrict__ Qb, unsigned short* __restrict__ Kb,
    unsigned short* __restrict__ Vt, float qscale)
{
    __shared__ unsigned short S[2 * 2 * 256 * 32];   // 64 KB (max of the two shapes)
    if (blockIdx.x < 512)
        gemm_body<0, 64, 2>(S, XA, WQT, bq, nullptr, Qb, nullptr, nullptr,
                            qscale, 4096, 1024, 1024, blockIdx.x, 512);
    else
        gemm_body<4, 128, 2>(S, M16, WKT, bk, bv, Kb, Vt, nullptr,
                             1.0f, 4096, 2048, 1024, blockIdx.x - 512, 512);
}

// ------------------------------------------------------------- attention PV
__global__ __launch_bounds__(256) void att_pv(
    const unsigned short* __restrict__ Q, const unsigned short* __restrict__ Kb,
    const unsigned short* __restrict__ Vt, unsigned short* __restrict__ O,
    float* __restrict__ LINV)
{
    __shared__ unsigned short Ks[2][2048];   // [32k][64d], swizzled 16B slots
    __shared__ unsigned short Vs[2][2048];   // [64d][32k], swizzled 16B slots
    const int tid = threadIdx.x, lane = tid & 63, wave = tid >> 6;
    const int g = lane >> 4, q16 = lane & 15;
    const int bh = blockIdx.x & 63;     // stride-64 blocks share (b,h) -> same XCD
    const int qt = blockIdx.x >> 6;     // 0..7
    const int b = bh >> 4, h = bh & 15;
    const int qbase = qt * 128 + wave * 32;

    const int rowK = wave * 8 + (lane >> 3);          // k-row within chunk
    const int cK   = (lane & 7) ^ (rowK & 7);         // swizzled 16B slot
    const int rowV = wave * 16 + (lane >> 2);         // d-row
    const int cV   = (lane & 3) ^ (rowV & 3);
    const unsigned short* kSrc = Kb + ((size_t)(b * 1024 + rowK)) * 1024 + h * 64 + cK * 8;
    const unsigned short* vSrc = Vt + ((size_t)(bh * 64 + rowV)) * 1024 + cV * 8;

    short8 qf[2][2];
    #pragma unroll
    for (int nf = 0; nf < 2; nf++)
        #pragma unroll
        for (int ds = 0; ds < 2; ds++)
            qf[nf][ds] = *(const short8*)(Q + (size_t)(b * 1024 + qbase + nf * 16 + q16) * 1024 + h * 64 + ds * 32 + g * 8);

    f32x4 oacc[4][2] = {};
    float lsum[2] = {0.f, 0.f};

    auto STAGE = [&](int buf, int kc) {
        __builtin_amdgcn_global_load_lds((const AS1 unsigned int*)(kSrc + (size_t)kc * 1024),
                                         (AS3 unsigned int*)(&Ks[buf][0] + wave * 512), 16, 0, 0);
        __builtin_amdgcn_global_load_lds((const AS1 unsigned int*)(vSrc + kc),
                                         (AS3 unsigned int*)(&Vs[buf][0] + wave * 512), 16, 0, 0);
    };
    auto BODY = [&](int buf) {
        short8 kf[2][2], vf[4];
        #pragma unroll
        for (int kt = 0; kt < 2; kt++)
            #pragma unroll
            for (int ds = 0; ds < 2; ds++)
                kf[kt][ds] = *(const short8*)(&Ks[buf][0] + (kt * 16 + q16) * 64 + ((ds * 4 + g) ^ (q16 & 7)) * 8);
        #pragma unroll
        for (int mf = 0; mf < 4; mf++)
            vf[mf] = *(const short8*)(&Vs[buf][0] + (mf * 16 + q16) * 32 + (g ^ (q16 & 3)) * 8);
        f32x4 sacc[2][2] = {};
        #pragma unroll
        for (int kt = 0; kt < 2; kt++)
            #pragma unroll
            for (int nf = 0; nf < 2; nf++) {
                sacc[kt][nf] = __builtin_amdgcn_mfma_f32_16x16x32_bf16(kf[kt][0], qf[nf][0], sacc[kt][nf], 0, 0, 0);
                sacc[kt][nf] = __builtin_amdgcn_mfma_f32_16x16x32_bf16(kf[kt][1], qf[nf][1], sacc[kt][nf], 0, 0, 0);
            }
        float ps[2][2][4];
        #pragma unroll
        for (int kt = 0; kt < 2; kt++)
            #pragma unroll
            for (int nf = 0; nf < 2; nf++)
                #pragma unroll
                for (int r = 0; r < 4; r++)
                    ps[kt][nf][r] = exp2_hw(sacc[kt][nf][r]);
        #pragma unroll
        for (int nf = 0; nf < 2; nf++)
            lsum[nf] += ps[0][nf][0] + ps[0][nf][1] + ps[0][nf][2] + ps[0][nf][3]
                      + ps[1][nf][0] + ps[1][nf][1] + ps[1][nf][2] + ps[1][nf][3];
        short8 pbf[2];
        #pragma unroll
        for (int nf = 0; nf < 2; nf++) {
            pbf[nf][0] = (short)f2bf(ps[0][nf][0]);
            pbf[nf][1] = (short)f2bf(ps[0][nf][1]);
            pbf[nf][2] = (short)f2bf(ps[0][nf][2]);
            pbf[nf][3] = (short)f2bf(ps[0][nf][3]);
            pbf[nf][4] = (short)f2bf(ps[1][nf][0]);
            pbf[nf][5] = (short)f2bf(ps[1][nf][1]);
            pbf[nf][6] = (short)f2bf(ps[1][nf][2]);
            pbf[nf][7] = (short)f2bf(ps[1][nf][3]);
        }
        #pragma unroll
        for (int mf = 0; mf < 4; mf++)
            #pragma unroll
            for (int nf = 0; nf < 2; nf++)
                oacc[mf][nf] = __builtin_amdgcn_mfma_f32_16x16x32_bf16(vf[mf], pbf[nf], oacc[mf][nf], 0, 0, 0);
    };

    STAGE(0, 0);
    __syncthreads();                 // buf0 staged
    int buf = 0;
    #pragma unroll 1
    for (int kc = 0; kc < 1024; kc += 32) {
        if (kc + 32 < 1024) STAGE(buf ^ 1, kc + 32);   // flies under BODY
        BODY(buf);
        __syncthreads();             // next buf ready; cur free for overwrite
        buf ^= 1;
    }
    #pragma unroll
    for (int nf = 0; nf < 2; nf++) {               // deferred cross-lane reduce
        lsum[nf] += __shfl_xor(lsum[nf], 16);
        lsum[nf] += __shfl_xor(lsum[nf], 32);
    }

    #pragma unroll
    for (int nf = 0; nf < 2; nf++) {
        const float inv = 1.0f / lsum[nf];
        if (g == 0) LINV[(size_t)bh * 1024 + qbase + nf * 16 + q16] = inv;
        #pragma unroll
        for (int mf = 0; mf < 4; mf++) {
            u16x4 o;
            #pragma unroll
            for (int r = 0; r < 4; r++) o[r] = f2bf(oacc[mf][nf][r] * inv);
            *(u16x4*)(O + (size_t)(b * 1024 + qbase + nf * 16 + q16) * 1024 + h * 64 + mf * 16 + g * 4) = o;
        }
    }
}

// -------------------------------------- head-averaged attn output (body form)
__device__ __forceinline__ void att_mean_body(
    unsigned short* Qs,     // >= 2*2048 shorts of LDS scratch
    const unsigned short* __restrict__ Q, const unsigned short* __restrict__ Kb,
    const float* __restrict__ LINV, float* __restrict__ out1, int vbid)
{
    const int tid = threadIdx.x;
    const int lane = tid & 63, wave = tid >> 6;
    const int g = lane >> 4, q16 = lane & 15;
    const int kb = vbid & 7;
    const int qb = (vbid >> 3) & 31;
    const int b = vbid >> 8;
    const int qbase = qb * 32;
    const int kbase = kb * 128 + wave * 32;

    const int rowQ = wave * 8 + (lane >> 3);
    const int cQ   = (lane & 7) ^ (rowQ & 7);
    const unsigned short* qSrc = Q + (size_t)(b * 1024 + qbase + rowQ) * 1024 + cQ * 8;

    f32x4 facc[2][2] = {};

    auto STAGE = [&](int buf, int h) {
        __builtin_amdgcn_global_load_lds((const AS1 unsigned int*)(qSrc + h * 64),
                                         (AS3 unsigned int*)(Qs + buf * 2048 + wave * 512), 16, 0, 0);
    };
    auto LOADK = [&](short8 (&kf)[2][2], f32x4 (&li)[2], int h) {
        #pragma unroll
        for (int nf = 0; nf < 2; nf++)
            #pragma unroll
            for (int ds = 0; ds < 2; ds++)
                kf[nf][ds] = *(const short8*)(Kb + (size_t)(b * 1024 + kbase + nf * 16 + q16) * 1024 + h * 64 + ds * 32 + g * 8);
        const float* lp = LINV + (size_t)(b * 16 + h) * 1024 + qbase;
        #pragma unroll
        for (int mf = 0; mf < 2; mf++)
            li[mf] = *(const f32x4*)(lp + mf * 16 + g * 4);
    };
    auto COMP = [&](int buf, short8 (&kf)[2][2], f32x4 (&li)[2]) {
        short8 qfr[2][2];
        #pragma unroll
        for (int mf = 0; mf < 2; mf++)
            #pragma unroll
            for (int ds = 0; ds < 2; ds++)
                qfr[mf][ds] = *(const short8*)(Qs + buf * 2048 + (mf * 16 + q16) * 64 + ((ds * 4 + g) ^ (q16 & 7)) * 8);
        #pragma unroll
        for (int nf = 0; nf < 2; nf++) {
            f32x4 sacc[2] = {};
            #pragma unroll
            for (int mf = 0; mf < 2; mf++) {
                sacc[mf] = __builtin_amdgcn_mfma_f32_16x16x32_bf16(qfr[mf][0], kf[nf][0], sacc[mf], 0, 0, 0);
                sacc[mf] = __builtin_amdgcn_mfma_f32_16x16x32_bf16(qfr[mf][1], kf[nf][1], sacc[mf], 0, 0, 0);
            }
            #pragma unroll
            for (int mf = 0; mf < 2; mf++)
                #pragma unroll
                for (int r = 0; r < 4; r++)
                    facc[mf][nf][r] = fmaf(exp2_hw(sacc[mf][r]), li[mf][r], facc[mf][nf][r]);
        }
    };

    short8 kA[2][2], kB[2][2];
    f32x4 liA[2], liB[2];
    STAGE(0, 0); LOADK(kA, liA, 0);
    __syncthreads();                     // buf0 staged
    #pragma unroll 1
    for (int h = 0; h < 16; h += 2) {
        STAGE(1, h + 1); LOADK(kB, liB, h + 1);     // fly under COMP(buf0)
        COMP(0, kA, liA);
        __syncthreads();                 // buf1 staged; buf0 reads done
        if (h + 2 < 16) { STAGE(0, h + 2); LOADK(kA, liA, h + 2); }
        COMP(1, kB, liB);
        __syncthreads();                 // buf0 staged; buf1 reads done
    }

    #pragma unroll
    for (int mf = 0; mf < 2; mf++)
        #pragma unroll
        for (int nf = 0; nf < 2; nf++)
            #pragma unroll
            for (int r = 0; r < 4; r++)
                out1[(size_t)(b * 1024 + qbase + mf * 16 + g * 4 + r) * 1024 + kbase + nf * 16 + q16]
                    = facc[mf][nf][r] * 0.0625f;
}

// ------- fused WO-projection + att_mean (independent after att_pv):
// blocks [0,512) = WO GEMM (xout = tgt + O*WO + bo); [512,1536) = att_mean.
// Co-scheduling the two latency-bound kernels fills each other's stalls.
__global__ __launch_bounds__(256) void wo_attmean_fused(
    const unsigned short* __restrict__ O16, const unsigned short* __restrict__ WOT,
    const float* __restrict__ bo, float* __restrict__ xout, const float* __restrict__ tgt,
    const unsigned short* __restrict__ Qb, const unsigned short* __restrict__ Kb,
    const float* __restrict__ LNV, float* __restrict__ attn)
{
    __shared__ unsigned short S[2 * 2 * (128 + 64) * 32];   // 48 KB (WO shape; att_mean uses 8 KB)
    if (blockIdx.x < 512)
        gemm_body<3, 64, 2>(S, O16, WOT, bo, nullptr, xout, nullptr, tgt,
                            1.0f, 4096, 1024, 1024, blockIdx.x, 512);
    else
        att_mean_body(S, Qb, Kb, LNV, attn, blockIdx.x - 512);
}

// ---------------------------------------------------------------- launcher
extern "C" void kernel_launch(void* const* d_in, const int* in_sizes, int n_in,
                              void* d_out, int out_size, void* d_ws, size_t ws_size,
                              hipStream_t stream)
{
    (void)in_sizes; (void)n_in; (void)out_size; (void)ws_size;
    const float* tgt  = (const float*)d_in[0];
    const float* mem  = (const float*)d_in[1];
    const float* ln1g = (const float*)d_in[2];
    const float* ln1b = (const float*)d_in[3];
    const float* wq   = (const float*)d_in[4];
    const float* bq   = (const float*)d_in[5];
    const float* wk   = (const float*)d_in[6];
    const float* bk   = (const float*)d_in[7];
    const float* wv   = (const float*)d_in[8];
    const float* bv   = (const float*)d_in[9];
    const float* wo   = (const float*)d_in[10];
    const float* bo   = (const float*)d_in[11];
    const float* ln3g = (const float*)d_in[12];
    const float* ln3b = (const float*)d_in[13];
    const float* w1   = (const float*)d_in[14];
    const float* b1   = (const float*)d_in[15];
    const float* w2   = (const float*)d_in[16];
    const float* b2   = (const float*)d_in[17];

    char* ws = (char*)d_ws;
    unsigned short* XA  = (unsigned short*)(ws);                  // 8 MB (t2, later t3)
    unsigned short* M16 = (unsigned short*)(ws + ((size_t)8  << 20));
    unsigned short* WQT = (unsigned short*)(ws + ((size_t)16 << 20));
    unsigned short* WKT = (unsigned short*)(ws + ((size_t)18 << 20)); // [WKT;WVT] = fused 2048xK
    unsigned short* WVT = (unsigned short*)(ws + ((size_t)20 << 20));
    unsigned short* WOT = (unsigned short*)(ws + ((size_t)22 << 20));
    unsigned short* W1T = (unsigned short*)(ws + ((size_t)24 << 20)); // 8 MB
    unsigned short* W2T = (unsigned short*)(ws + ((size_t)32 << 20)); // 8 MB
    unsigned short* Qb  = (unsigned short*)(ws + ((size_t)40 << 20));
    unsigned short* Kb  = (unsigned short*)(ws + ((size_t)48 << 20));
    unsigned short* Vt  = (unsigned short*)(ws + ((size_t)56 << 20));
    unsigned short* O16 = (unsigned short*)(ws + ((size_t)64 << 20));
    unsigned short* H16 = (unsigned short*)(ws + ((size_t)72 << 20)); // 32 MB
    float*          LNV = (float*)(ws + ((size_t)104 << 20));         // 256 KB
    float* xout = (float*)d_out;                       // x then x+ffn [4096][1024]
    float* attn = xout + (size_t)4 * 1024 * 1024;      // [4][1024][1024]

    const float QSCALE = 0.125f * 1.4426950408889634f;   // fold softmax scale + log2e into Q

    prep_fused<<<20480, 256, 0, stream>>>(tgt, ln1g, ln1b, XA, mem, M16,
                                          wq, wk, wv, wo, WQT, WKT, WVT, WOT,
                                          w1, W1T, w2, W2T);

    // fused Q (prescaled, EPI0/BN64) + KV (EPI4/BN128) projections, grid 1024
    qkv_fused<<<1024, 256, 0, stream>>>(XA, WQT, bq, M16, WKT, bk, bv, Qb, Kb, Vt, QSCALE);

    att_pv<<<512, 256, 0, stream>>>(Qb, Kb, Vt, O16, LNV);

    // WO GEMM (512 blocks) + att_mean (1024 blocks) co-scheduled: independent
    wo_attmean_fused<<<1536, 256, 0, stream>>>(O16, WOT, bo, xout, tgt,
                                               Qb, Kb, LNV, attn);

    ln_to_bf16<<<4096, 256, 0, stream>>>(xout, ln3g, ln3b, XA);
    // FFN1: N=4096, BN=128, PF=2 -> grid 1024
    gemm_single<2, 128, 2><<<32 * 32, 256, 0, stream>>>(XA, W1T, b1, nullptr, H16, nullptr, nullptr, 1.0f, 4096, 4096, 1024);
    // FFN2: ring3 @ BN=64 (r15-proven best), grid 512
    gemm_ring3<3, 64, 2><<<32 * 16, 256, 0, stream>>>(H16, W2T, b2, nullptr, xout, nullptr, xout, 1.0f, 4096, 1024, 4096);
}